// Round 1
// baseline (2504.841 us; speedup 1.0000x reference)
//
#include <hip/hip_runtime.h>

#define NNODES 50000
#define NEDGES 800000
#define NSLOPE 0.2f

__device__ __forceinline__ float lrelu(float x) { return x > 0.f ? x : NSLOPE * x; }

// ---------------- GEMM: A[nrows,128] @ W[128,NCOL] -> H[nrows,NCOL] ----------------
// 256 threads/block; groups of NCOL/4 lanes; each thread: 4 rows x 4 cols.
template<int NCOL>
__global__ void gemm_kernel(const float* __restrict__ A, const float* __restrict__ W,
                            float* __restrict__ H, int nrows) {
    constexpr int LG = NCOL / 4;        // lanes per group
    constexpr int GROUPS = 256 / LG;    // groups per block
    int tid = threadIdx.x;
    int g = tid / LG, l = tid % LG;
    int c = l * 4;
    long r0 = (long)blockIdx.x * (GROUPS * 4) + (long)g * 4;
    if (r0 >= nrows) return;
    float4 acc[4];
#pragma unroll
    for (int i = 0; i < 4; i++) acc[i] = make_float4(0.f, 0.f, 0.f, 0.f);
    long rr[4];
#pragma unroll
    for (int i = 0; i < 4; i++) { long r = r0 + i; rr[i] = (r < nrows) ? r : (long)(nrows - 1); }
    for (int k0 = 0; k0 < 128; k0 += 4) {
        float4 w0 = *(const float4*)&W[(k0 + 0) * NCOL + c];
        float4 w1 = *(const float4*)&W[(k0 + 1) * NCOL + c];
        float4 w2 = *(const float4*)&W[(k0 + 2) * NCOL + c];
        float4 w3 = *(const float4*)&W[(k0 + 3) * NCOL + c];
#pragma unroll
        for (int i = 0; i < 4; i++) {
            float4 xv = *(const float4*)&A[rr[i] * 128 + k0];
            acc[i].x += xv.x * w0.x + xv.y * w1.x + xv.z * w2.x + xv.w * w3.x;
            acc[i].y += xv.x * w0.y + xv.y * w1.y + xv.z * w2.y + xv.w * w3.y;
            acc[i].z += xv.x * w0.z + xv.y * w1.z + xv.z * w2.z + xv.w * w3.z;
            acc[i].w += xv.x * w0.w + xv.y * w1.w + xv.z * w2.w + xv.w * w3.w;
        }
    }
#pragma unroll
    for (int i = 0; i < 4; i++) {
        if (r0 + i < nrows) *(float4*)&H[(r0 + i) * NCOL + c] = acc[i];
    }
}

// ---------------- attention dot products: a_src[n,h], a_dst[n,h] ----------------
template<int HEADS, int CH>
__global__ void att_dot_kernel(const float* __restrict__ H, const float* __restrict__ att_s,
                               const float* __restrict__ att_d, float* __restrict__ as_,
                               float* __restrict__ ad_, int n) {
    int t = blockIdx.x * 256 + threadIdx.x;
    if (t >= n * HEADS) return;
    int node = t / HEADS, h = t % HEADS;
    const float* hp = H + (long)node * HEADS * CH + h * CH;
    const float* sp = att_s + h * CH;
    const float* dp = att_d + h * CH;
    float ds = 0.f, dd = 0.f;
#pragma unroll
    for (int c = 0; c < CH; c += 4) {
        float4 hv = *(const float4*)&hp[c];
        float4 sv = *(const float4*)&sp[c];
        float4 dv = *(const float4*)&dp[c];
        ds += hv.x * sv.x + hv.y * sv.y + hv.z * sv.z + hv.w * sv.w;
        dd += hv.x * dv.x + hv.y * dv.y + hv.z * dv.z + hv.w * dv.w;
    }
    as_[t] = ds;
    ad_[t] = dd;
}

// ---------------- edge pass A: denom[dst,h] += exp(lrelu(a_src[s]+a_dst[d])) ----------------
template<int HEADS>
__global__ void edge_denom_kernel(const int* __restrict__ ei, const float* __restrict__ as_,
                                  const float* __restrict__ ad_, float* __restrict__ denom) {
    int t = blockIdx.x * 256 + threadIdx.x;
    if (t >= NEDGES + NNODES) return;
    int s, d;
    if (t < NEDGES) { s = ei[t]; d = ei[NEDGES + t]; } else { s = d = t - NEDGES; }
#pragma unroll
    for (int h = 0; h < HEADS; h++) {
        float a = lrelu(as_[s * HEADS + h] + ad_[d * HEADS + h]);
        atomicAdd(&denom[d * HEADS + h], __expf(a));
    }
}

// ---------------- edge pass B: out[dst] += h[src] * exp(..)/denom[dst] ----------------
// one thread per (edge, 4 channels)
template<int HEADS, int NCOL>
__global__ void edge_aggr_kernel(const int* __restrict__ ei, const float* __restrict__ as_,
                                 const float* __restrict__ ad_, const float* __restrict__ denom,
                                 const float* __restrict__ H, float* __restrict__ out) {
    constexpr int PER = NCOL / 4;
    long t = (long)blockIdx.x * 256 + threadIdx.x;
    long e = t / PER;
    int j = (int)(t % PER);
    if (e >= NEDGES + NNODES) return;
    int s, d;
    if (e < NEDGES) { s = ei[e]; d = ei[NEDGES + e]; } else { s = d = (int)(e - NEDGES); }
    int c = j * 4;
    int h = (HEADS == 1) ? 0 : (c >> 5);
    float a = lrelu(as_[s * HEADS + h] + ad_[d * HEADS + h]);
    float w = __expf(a) / (denom[d * HEADS + h] + 1e-16f);
    float4 hv = *(const float4*)&H[(long)s * NCOL + c];
    float* op = out + (long)d * NCOL + c;
    atomicAdd(op + 0, hv.x * w);
    atomicAdd(op + 1, hv.y * w);
    atomicAdd(op + 2, hv.z * w);
    atomicAdd(op + 3, hv.w * w);
}

// ---------------- misc elementwise ----------------
__global__ void bias_init_kernel(float* __restrict__ out, const float* __restrict__ b,
                                 long total, int C) {
    long t = (long)blockIdx.x * 256 + threadIdx.x;
    if (t < total) out[t] = b[t % C];
}

__global__ void lrelu_kernel(float* __restrict__ x, long total) {
    long t = (long)blockIdx.x * 256 + threadIdx.x;
    if (t < total) x[t] = lrelu(x[t]);
}

static inline int nblk(long total) { return (int)((total + 255) / 256); }

extern "C" void kernel_launch(void* const* d_in, const int* in_sizes, int n_in,
                              void* d_out, int out_size, void* d_ws, size_t ws_size,
                              hipStream_t stream) {
    const float* x     = (const float*)d_in[0];
    const int*   ei    = (const int*)d_in[1];   // [2, NEDGES]: row 0 = src, row 1 = dst
    const float* W1    = (const float*)d_in[2];
    const float* as1w  = (const float*)d_in[3];
    const float* ad1w  = (const float*)d_in[4];
    const float* b1    = (const float*)d_in[5];
    const float* W2    = (const float*)d_in[6];
    const float* as2w  = (const float*)d_in[7];
    const float* ad2w  = (const float*)d_in[8];
    const float* b2    = (const float*)d_in[9];
    float* out = (float*)d_out;

    float* ws = (float*)d_ws;
    long o = 0;
    float* h1     = ws + o; o += (long)NNODES * 128;
    float* x2     = ws + o; o += (long)NNODES * 128;   // layer-1 aggregated output / layer-2 input
    float* h2     = ws + o; o += (long)NNODES * 64;
    float* a_src1 = ws + o; o += (long)NNODES * 4;
    float* a_dst1 = ws + o; o += (long)NNODES * 4;
    float* a_src2 = ws + o; o += (long)NNODES;
    float* a_dst2 = ws + o; o += (long)NNODES;
    float* denom1 = ws + o; o += (long)NNODES * 4;     // denom1 & denom2 contiguous for one memset
    float* denom2 = ws + o; o += (long)NNODES;

    // zero denominators (5*N floats, contiguous)
    hipMemsetAsync(denom1, 0, sizeof(float) * (size_t)NNODES * 5, stream);
    // init aggregation targets with bias broadcast
    bias_init_kernel<<<nblk((long)NNODES * 128), 256, 0, stream>>>(x2, b1, (long)NNODES * 128, 128);
    bias_init_kernel<<<nblk((long)NNODES * 64), 256, 0, stream>>>(out, b2, (long)NNODES * 64, 64);

    // ---- layer 1 ----
    gemm_kernel<128><<<(NNODES + 31) / 32, 256, 0, stream>>>(x, W1, h1, NNODES);
    att_dot_kernel<4, 32><<<nblk((long)NNODES * 4), 256, 0, stream>>>(h1, as1w, ad1w, a_src1, a_dst1, NNODES);
    edge_denom_kernel<4><<<nblk(NEDGES + NNODES), 256, 0, stream>>>(ei, a_src1, a_dst1, denom1);
    edge_aggr_kernel<4, 128><<<nblk((long)(NEDGES + NNODES) * 32), 256, 0, stream>>>(
        ei, a_src1, a_dst1, denom1, h1, x2);
    lrelu_kernel<<<nblk((long)NNODES * 128), 256, 0, stream>>>(x2, (long)NNODES * 128);

    // ---- layer 2 ----
    gemm_kernel<64><<<(NNODES + 63) / 64, 256, 0, stream>>>(x2, W2, h2, NNODES);
    att_dot_kernel<1, 64><<<nblk((long)NNODES), 256, 0, stream>>>(h2, as2w, ad2w, a_src2, a_dst2, NNODES);
    edge_denom_kernel<1><<<nblk(NEDGES + NNODES), 256, 0, stream>>>(ei, a_src2, a_dst2, denom2);
    edge_aggr_kernel<1, 64><<<nblk((long)(NEDGES + NNODES) * 16), 256, 0, stream>>>(
        ei, a_src2, a_dst2, denom2, h2, out);
}

// Round 2
// 392.886 us; speedup vs baseline: 6.3755x; 6.3755x over previous
//
#include <hip/hip_runtime.h>

#define NNODES 50000
#define NEDGES 800000
#define NSLOPE 0.2f

__device__ __forceinline__ float lrelu(float x) { return x > 0.f ? x : NSLOPE * x; }

// ---------------- GEMM: A[nrows,128] @ W[128,NCOL] -> H[nrows,NCOL] ----------------
template<int NCOL>
__global__ void gemm_kernel(const float* __restrict__ A, const float* __restrict__ W,
                            float* __restrict__ H, int nrows) {
    constexpr int LG = NCOL / 4;        // lanes per group (cover all cols)
    constexpr int GROUPS = 256 / LG;    // row-groups per block
    int tid = threadIdx.x;
    int g = tid / LG, l = tid % LG;
    int c = l * 4;
    long r0 = (long)blockIdx.x * (GROUPS * 4) + (long)g * 4;
    if (r0 >= nrows) return;
    float4 acc[4];
#pragma unroll
    for (int i = 0; i < 4; i++) acc[i] = make_float4(0.f, 0.f, 0.f, 0.f);
    long rr[4];
#pragma unroll
    for (int i = 0; i < 4; i++) { long r = r0 + i; rr[i] = (r < nrows) ? r : (long)(nrows - 1); }
    for (int k0 = 0; k0 < 128; k0 += 4) {
        float4 w0 = *(const float4*)&W[(k0 + 0) * NCOL + c];
        float4 w1 = *(const float4*)&W[(k0 + 1) * NCOL + c];
        float4 w2 = *(const float4*)&W[(k0 + 2) * NCOL + c];
        float4 w3 = *(const float4*)&W[(k0 + 3) * NCOL + c];
#pragma unroll
        for (int i = 0; i < 4; i++) {
            float4 xv = *(const float4*)&A[rr[i] * 128 + k0];
            acc[i].x += xv.x * w0.x + xv.y * w1.x + xv.z * w2.x + xv.w * w3.x;
            acc[i].y += xv.x * w0.y + xv.y * w1.y + xv.z * w2.y + xv.w * w3.y;
            acc[i].z += xv.x * w0.z + xv.y * w1.z + xv.z * w2.z + xv.w * w3.z;
            acc[i].w += xv.x * w0.w + xv.y * w1.w + xv.z * w2.w + xv.w * w3.w;
        }
    }
#pragma unroll
    for (int i = 0; i < 4; i++) {
        if (r0 + i < nrows) *(float4*)&H[(r0 + i) * NCOL + c] = acc[i];
    }
}

// ---------------- attention dot products: a_src[n,h], a_dst[n,h] ----------------
template<int HEADS, int CH>
__global__ void att_dot_kernel(const float* __restrict__ H, const float* __restrict__ att_s,
                               const float* __restrict__ att_d, float* __restrict__ as_,
                               float* __restrict__ ad_, int n) {
    int t = blockIdx.x * 256 + threadIdx.x;
    if (t >= n * HEADS) return;
    int node = t / HEADS, h = t % HEADS;
    const float* hp = H + (long)node * HEADS * CH + h * CH;
    const float* sp = att_s + h * CH;
    const float* dp = att_d + h * CH;
    float ds = 0.f, dd = 0.f;
#pragma unroll
    for (int c = 0; c < CH; c += 4) {
        float4 hv = *(const float4*)&hp[c];
        float4 sv = *(const float4*)&sp[c];
        float4 dv = *(const float4*)&dp[c];
        ds += hv.x * sv.x + hv.y * sv.y + hv.z * sv.z + hv.w * sv.w;
        dd += hv.x * dv.x + hv.y * dv.y + hv.z * dv.z + hv.w * dv.w;
    }
    as_[t] = ds;
    ad_[t] = dd;
}

// ---------------- CSR build: histogram -> scan -> scatter ----------------
__global__ void hist_kernel(const int* __restrict__ ei, int* __restrict__ counts) {
    int e = blockIdx.x * 256 + threadIdx.x;
    if (e >= NEDGES) return;
    atomicAdd(&counts[ei[NEDGES + e]], 1);
}

__global__ void scan1_kernel(const int* __restrict__ counts, int* __restrict__ offs,
                             int* __restrict__ bsums, int n) {
    __shared__ int tmp[256];
    int i = blockIdx.x * 256 + threadIdx.x;
    int v = (i < n) ? counts[i] : 0;
    tmp[threadIdx.x] = v;
    __syncthreads();
    for (int off = 1; off < 256; off <<= 1) {
        int t = (threadIdx.x >= off) ? tmp[threadIdx.x - off] : 0;
        __syncthreads();
        tmp[threadIdx.x] += t;
        __syncthreads();
    }
    if (i < n) offs[i] = tmp[threadIdx.x] - v;   // exclusive within block
    if (threadIdx.x == 255) bsums[blockIdx.x] = tmp[255];
}

__global__ void scan2_kernel(int* __restrict__ bsums, int nb) {
    __shared__ int tmp[256];
    int v = (threadIdx.x < nb) ? bsums[threadIdx.x] : 0;
    tmp[threadIdx.x] = v;
    __syncthreads();
    for (int off = 1; off < 256; off <<= 1) {
        int t = (threadIdx.x >= off) ? tmp[threadIdx.x - off] : 0;
        __syncthreads();
        tmp[threadIdx.x] += t;
        __syncthreads();
    }
    if (threadIdx.x < nb) bsums[threadIdx.x] = tmp[threadIdx.x] - v;  // exclusive
}

__global__ void scan3_kernel(int* __restrict__ offs, const int* __restrict__ bsums,
                             int* __restrict__ cursor, int n) {
    int i = blockIdx.x * 256 + threadIdx.x;
    if (i >= n) return;
    int o = offs[i] + bsums[blockIdx.x];
    offs[i] = o;
    cursor[i] = o;
}

__global__ void scatter_kernel(const int* __restrict__ ei, int* __restrict__ cursor,
                               int* __restrict__ ssrc) {
    int e = blockIdx.x * 256 + threadIdx.x;
    if (e >= NEDGES) return;
    int s = ei[e], d = ei[NEDGES + e];
    int pos = atomicAdd(&cursor[d], 1);
    ssrc[pos] = s;
}

// ---------------- gather: one wave per dst node, single pass, fused epilogue ------
// accumulates unnormalized sum + denom; normalizes once. Self-loop handled inline.
// after scatter, cursor[d] == offs[d] + count[d] == end of d's segment.
template<int HEADS, int NCOL, int LRELU>
__global__ void gather_kernel(const int* __restrict__ ssrc, const int* __restrict__ offs,
                              const int* __restrict__ ends, const float* __restrict__ as_,
                              const float* __restrict__ ad_, const float* __restrict__ H,
                              const float* __restrict__ bias, float* __restrict__ out, int n) {
    constexpr int VPL = NCOL / 64;   // floats per lane: 2 for NCOL=128, 1 for NCOL=64
    int wave = (blockIdx.x * blockDim.x + threadIdx.x) >> 6;
    if (wave >= n) return;
    int lane = threadIdx.x & 63;
    int d = wave;
    int c = lane * VPL;
    int h = (HEADS == 1) ? 0 : (c * HEADS / NCOL);
    float acc0 = 0.f, acc1 = 0.f, den = 0.f;
    float ad_d = ad_[d * HEADS + h];
    int start = offs[d], end = ends[d];
    for (int i = start; i < end; i++) {
        int s = ssrc[i];
        float w = __expf(lrelu(as_[s * HEADS + h] + ad_d));
        den += w;
        if (VPL == 2) {
            float2 hv = *(const float2*)&H[(long)s * NCOL + c];
            acc0 += w * hv.x; acc1 += w * hv.y;
        } else {
            acc0 += w * H[(long)s * NCOL + c];
        }
    }
    {   // self loop
        float w = __expf(lrelu(as_[d * HEADS + h] + ad_d));
        den += w;
        if (VPL == 2) {
            float2 hv = *(const float2*)&H[(long)d * NCOL + c];
            acc0 += w * hv.x; acc1 += w * hv.y;
        } else {
            acc0 += w * H[(long)d * NCOL + c];
        }
    }
    float inv = 1.f / (den + 1e-16f);
    if (VPL == 2) {
        float r0 = acc0 * inv + bias[c];
        float r1 = acc1 * inv + bias[c + 1];
        if (LRELU) { r0 = lrelu(r0); r1 = lrelu(r1); }
        float2 r = make_float2(r0, r1);
        *(float2*)&out[(long)d * NCOL + c] = r;
    } else {
        float r0 = acc0 * inv + bias[c];
        if (LRELU) r0 = lrelu(r0);
        out[(long)d * NCOL + c] = r0;
    }
}

static inline int nblk(long total) { return (int)((total + 255) / 256); }

extern "C" void kernel_launch(void* const* d_in, const int* in_sizes, int n_in,
                              void* d_out, int out_size, void* d_ws, size_t ws_size,
                              hipStream_t stream) {
    const float* x    = (const float*)d_in[0];
    const int*   ei   = (const int*)d_in[1];   // [2, NEDGES]
    const float* W1   = (const float*)d_in[2];
    const float* as1w = (const float*)d_in[3];
    const float* ad1w = (const float*)d_in[4];
    const float* b1   = (const float*)d_in[5];
    const float* W2   = (const float*)d_in[6];
    const float* as2w = (const float*)d_in[7];
    const float* ad2w = (const float*)d_in[8];
    const float* b2   = (const float*)d_in[9];
    float* out = (float*)d_out;

    float* ws = (float*)d_ws;
    long o = 0;
    float* h1     = ws + o; o += (long)NNODES * 128;   // layer-1 features; h2 aliases this
    float* x2     = ws + o; o += (long)NNODES * 128;   // layer-1 output / layer-2 input
    float* a_src1 = ws + o; o += (long)NNODES * 4;
    float* a_dst1 = ws + o; o += (long)NNODES * 4;
    float* a_src2 = ws + o; o += (long)NNODES;
    float* a_dst2 = ws + o; o += (long)NNODES;
    int* counts = (int*)(ws + o); o += NNODES;
    int* offs   = (int*)(ws + o); o += NNODES;
    int* cursor = (int*)(ws + o); o += NNODES;
    int* bsums  = (int*)(ws + o); o += 256;
    int* ssrc   = (int*)(ws + o); o += NEDGES;
    float* h2 = h1;   // reuse: h1 dead after layer-1 gather

    const int NB = (NNODES + 255) / 256;   // scan blocks (196)

    // ---- CSR build (dst-sorted src list) ----
    hipMemsetAsync(counts, 0, sizeof(int) * NNODES, stream);
    hist_kernel<<<nblk(NEDGES), 256, 0, stream>>>(ei, counts);
    scan1_kernel<<<NB, 256, 0, stream>>>(counts, offs, bsums, NNODES);
    scan2_kernel<<<1, 256, 0, stream>>>(bsums, NB);
    scan3_kernel<<<NB, 256, 0, stream>>>(offs, bsums, cursor, NNODES);
    scatter_kernel<<<nblk(NEDGES), 256, 0, stream>>>(ei, cursor, ssrc);

    // ---- layer 1 ----
    gemm_kernel<128><<<(NNODES + 31) / 32, 256, 0, stream>>>(x, W1, h1, NNODES);
    att_dot_kernel<4, 32><<<nblk((long)NNODES * 4), 256, 0, stream>>>(h1, as1w, ad1w, a_src1, a_dst1, NNODES);
    gather_kernel<4, 128, 1><<<nblk((long)NNODES * 64), 256, 0, stream>>>(
        ssrc, offs, cursor, a_src1, a_dst1, h1, b1, x2, NNODES);

    // ---- layer 2 ----
    gemm_kernel<64><<<(NNODES + 63) / 64, 256, 0, stream>>>(x2, W2, h2, NNODES);
    att_dot_kernel<1, 64><<<nblk((long)NNODES), 256, 0, stream>>>(h2, as2w, ad2w, a_src2, a_dst2, NNODES);
    gather_kernel<1, 64, 0><<<nblk((long)NNODES * 64), 256, 0, stream>>>(
        ssrc, offs, cursor, a_src2, a_dst2, h2, b2, out, NNODES);
}

// Round 3
// 313.446 us; speedup vs baseline: 7.9913x; 1.2534x over previous
//
#include <hip/hip_runtime.h>

#define NNODES 50000
#define NEDGES 800000
#define NSLOPE 0.2f

__device__ __forceinline__ float lrelu(float x) { return x > 0.f ? x : NSLOPE * x; }

// ---------------- GEMM: A[nrows,128] @ W[128,NCOL] -> H[nrows,NCOL] ----------------
template<int NCOL>
__global__ void gemm_kernel(const float* __restrict__ A, const float* __restrict__ W,
                            float* __restrict__ H, int nrows) {
    constexpr int LG = NCOL / 4;        // lanes per group (cover all cols)
    constexpr int GROUPS = 256 / LG;    // row-groups per block
    int tid = threadIdx.x;
    int g = tid / LG, l = tid % LG;
    int c = l * 4;
    long r0 = (long)blockIdx.x * (GROUPS * 4) + (long)g * 4;
    if (r0 >= nrows) return;
    float4 acc[4];
#pragma unroll
    for (int i = 0; i < 4; i++) acc[i] = make_float4(0.f, 0.f, 0.f, 0.f);
    long rr[4];
#pragma unroll
    for (int i = 0; i < 4; i++) { long r = r0 + i; rr[i] = (r < nrows) ? r : (long)(nrows - 1); }
    for (int k0 = 0; k0 < 128; k0 += 4) {
        float4 w0 = *(const float4*)&W[(k0 + 0) * NCOL + c];
        float4 w1 = *(const float4*)&W[(k0 + 1) * NCOL + c];
        float4 w2 = *(const float4*)&W[(k0 + 2) * NCOL + c];
        float4 w3 = *(const float4*)&W[(k0 + 3) * NCOL + c];
#pragma unroll
        for (int i = 0; i < 4; i++) {
            float4 xv = *(const float4*)&A[rr[i] * 128 + k0];
            acc[i].x += xv.x * w0.x + xv.y * w1.x + xv.z * w2.x + xv.w * w3.x;
            acc[i].y += xv.x * w0.y + xv.y * w1.y + xv.z * w2.y + xv.w * w3.y;
            acc[i].z += xv.x * w0.z + xv.y * w1.z + xv.z * w2.z + xv.w * w3.z;
            acc[i].w += xv.x * w0.w + xv.y * w1.w + xv.z * w2.w + xv.w * w3.w;
        }
    }
#pragma unroll
    for (int i = 0; i < 4; i++) {
        if (r0 + i < nrows) *(float4*)&H[(r0 + i) * NCOL + c] = acc[i];
    }
}

// ---------------- attention dot products: a_src[n,h], a_dst[n,h] ----------------
template<int HEADS, int CH>
__global__ void att_dot_kernel(const float* __restrict__ H, const float* __restrict__ att_s,
                               const float* __restrict__ att_d, float* __restrict__ as_,
                               float* __restrict__ ad_, int n) {
    int t = blockIdx.x * 256 + threadIdx.x;
    if (t >= n * HEADS) return;
    int node = t / HEADS, h = t % HEADS;
    const float* hp = H + (long)node * HEADS * CH + h * CH;
    const float* sp = att_s + h * CH;
    const float* dp = att_d + h * CH;
    float ds = 0.f, dd = 0.f;
#pragma unroll
    for (int c = 0; c < CH; c += 4) {
        float4 hv = *(const float4*)&hp[c];
        float4 sv = *(const float4*)&sp[c];
        float4 dv = *(const float4*)&dp[c];
        ds += hv.x * sv.x + hv.y * sv.y + hv.z * sv.z + hv.w * sv.w;
        dd += hv.x * dv.x + hv.y * dv.y + hv.z * dv.z + hv.w * dv.w;
    }
    as_[t] = ds;
    ad_[t] = dd;
}

// ---------------- CSR build: histogram -> scan -> scatter ----------------
__global__ void hist_kernel(const int* __restrict__ ei, int* __restrict__ counts) {
    int e = blockIdx.x * 256 + threadIdx.x;
    if (e >= NEDGES) return;
    atomicAdd(&counts[ei[NEDGES + e]], 1);
}

__global__ void scan1_kernel(const int* __restrict__ counts, int* __restrict__ offs,
                             int* __restrict__ bsums, int n) {
    __shared__ int tmp[256];
    int i = blockIdx.x * 256 + threadIdx.x;
    int v = (i < n) ? counts[i] : 0;
    tmp[threadIdx.x] = v;
    __syncthreads();
    for (int off = 1; off < 256; off <<= 1) {
        int t = (threadIdx.x >= off) ? tmp[threadIdx.x - off] : 0;
        __syncthreads();
        tmp[threadIdx.x] += t;
        __syncthreads();
    }
    if (i < n) offs[i] = tmp[threadIdx.x] - v;   // exclusive within block
    if (threadIdx.x == 255) bsums[blockIdx.x] = tmp[255];
}

__global__ void scan2_kernel(int* __restrict__ bsums, int nb) {
    __shared__ int tmp[256];
    int v = (threadIdx.x < nb) ? bsums[threadIdx.x] : 0;
    tmp[threadIdx.x] = v;
    __syncthreads();
    for (int off = 1; off < 256; off <<= 1) {
        int t = (threadIdx.x >= off) ? tmp[threadIdx.x - off] : 0;
        __syncthreads();
        tmp[threadIdx.x] += t;
        __syncthreads();
    }
    if (threadIdx.x < nb) bsums[threadIdx.x] = tmp[threadIdx.x] - v;  // exclusive
}

__global__ void scan3_kernel(int* __restrict__ offs, const int* __restrict__ bsums,
                             int* __restrict__ cursor, int n) {
    int i = blockIdx.x * 256 + threadIdx.x;
    if (i >= n) return;
    int o = offs[i] + bsums[blockIdx.x];
    offs[i] = o;
    cursor[i] = o;
}

__global__ void scatter_kernel(const int* __restrict__ ei, int* __restrict__ cursor,
                               int* __restrict__ ssrc) {
    int e = blockIdx.x * 256 + threadIdx.x;
    if (e >= NEDGES) return;
    int s = ei[e], d = ei[NEDGES + e];
    int pos = atomicAdd(&cursor[d], 1);
    ssrc[pos] = s;
}

// ---------------- gather: one wave per dst node ----------------
// Chunked: lanes cooperatively load 64 edge indices, broadcast via shfl.
// 8-way unrolled inner loop -> 8 independent H-row gathers in flight.
template<int HEADS, int NCOL, int LRELU>
__global__ void gather_kernel(const int* __restrict__ ssrc, const int* __restrict__ offs,
                              const int* __restrict__ ends, const float* __restrict__ as_,
                              const float* __restrict__ ad_, const float* __restrict__ H,
                              const float* __restrict__ bias, float* __restrict__ out, int n) {
    constexpr int VPL = NCOL / 64;   // floats per lane: 2 for NCOL=128, 1 for NCOL=64
    int wave = (blockIdx.x * blockDim.x + threadIdx.x) >> 6;
    if (wave >= n) return;
    int lane = threadIdx.x & 63;
    int d = wave;
    int c = lane * VPL;
    int h = (HEADS == 1) ? 0 : (c * HEADS / NCOL);
    float acc0 = 0.f, acc1 = 0.f, den = 0.f;
    float ad_d = ad_[d * HEADS + h];
    int start = offs[d], end = ends[d];

    for (int base = start; base < end; base += 64) {
        int m = end - base; if (m > 64) m = 64;
        int sv = (lane < m) ? ssrc[base + lane] : 0;
        int i = 0;
        for (; i + 8 <= m; i += 8) {
            int s0 = __shfl(sv, i + 0), s1 = __shfl(sv, i + 1);
            int s2 = __shfl(sv, i + 2), s3 = __shfl(sv, i + 3);
            int s4 = __shfl(sv, i + 4), s5 = __shfl(sv, i + 5);
            int s6 = __shfl(sv, i + 6), s7 = __shfl(sv, i + 7);
            float w0 = __expf(lrelu(as_[s0 * HEADS + h] + ad_d));
            float w1 = __expf(lrelu(as_[s1 * HEADS + h] + ad_d));
            float w2 = __expf(lrelu(as_[s2 * HEADS + h] + ad_d));
            float w3 = __expf(lrelu(as_[s3 * HEADS + h] + ad_d));
            float w4 = __expf(lrelu(as_[s4 * HEADS + h] + ad_d));
            float w5 = __expf(lrelu(as_[s5 * HEADS + h] + ad_d));
            float w6 = __expf(lrelu(as_[s6 * HEADS + h] + ad_d));
            float w7 = __expf(lrelu(as_[s7 * HEADS + h] + ad_d));
            den += ((w0 + w1) + (w2 + w3)) + ((w4 + w5) + (w6 + w7));
            if (VPL == 2) {
                float2 v0 = *(const float2*)&H[(long)s0 * NCOL + c];
                float2 v1 = *(const float2*)&H[(long)s1 * NCOL + c];
                float2 v2 = *(const float2*)&H[(long)s2 * NCOL + c];
                float2 v3 = *(const float2*)&H[(long)s3 * NCOL + c];
                float2 v4 = *(const float2*)&H[(long)s4 * NCOL + c];
                float2 v5 = *(const float2*)&H[(long)s5 * NCOL + c];
                float2 v6 = *(const float2*)&H[(long)s6 * NCOL + c];
                float2 v7 = *(const float2*)&H[(long)s7 * NCOL + c];
                acc0 += ((w0 * v0.x + w1 * v1.x) + (w2 * v2.x + w3 * v3.x))
                      + ((w4 * v4.x + w5 * v5.x) + (w6 * v6.x + w7 * v7.x));
                acc1 += ((w0 * v0.y + w1 * v1.y) + (w2 * v2.y + w3 * v3.y))
                      + ((w4 * v4.y + w5 * v5.y) + (w6 * v6.y + w7 * v7.y));
            } else {
                float v0 = H[(long)s0 * NCOL + c], v1 = H[(long)s1 * NCOL + c];
                float v2 = H[(long)s2 * NCOL + c], v3 = H[(long)s3 * NCOL + c];
                float v4 = H[(long)s4 * NCOL + c], v5 = H[(long)s5 * NCOL + c];
                float v6 = H[(long)s6 * NCOL + c], v7 = H[(long)s7 * NCOL + c];
                acc0 += ((w0 * v0 + w1 * v1) + (w2 * v2 + w3 * v3))
                      + ((w4 * v4 + w5 * v5) + (w6 * v6 + w7 * v7));
            }
        }
        for (; i < m; i++) {
            int s = __shfl(sv, i);
            float w = __expf(lrelu(as_[s * HEADS + h] + ad_d));
            den += w;
            if (VPL == 2) {
                float2 hv = *(const float2*)&H[(long)s * NCOL + c];
                acc0 += w * hv.x; acc1 += w * hv.y;
            } else {
                acc0 += w * H[(long)s * NCOL + c];
            }
        }
    }
    {   // self loop
        float w = __expf(lrelu(as_[d * HEADS + h] + ad_d));
        den += w;
        if (VPL == 2) {
            float2 hv = *(const float2*)&H[(long)d * NCOL + c];
            acc0 += w * hv.x; acc1 += w * hv.y;
        } else {
            acc0 += w * H[(long)d * NCOL + c];
        }
    }
    float inv = 1.f / (den + 1e-16f);
    if (VPL == 2) {
        float r0 = acc0 * inv + bias[c];
        float r1 = acc1 * inv + bias[c + 1];
        if (LRELU) { r0 = lrelu(r0); r1 = lrelu(r1); }
        *(float2*)&out[(long)d * NCOL + c] = make_float2(r0, r1);
    } else {
        float r0 = acc0 * inv + bias[c];
        if (LRELU) r0 = lrelu(r0);
        out[(long)d * NCOL + c] = r0;
    }
}

static inline int nblk(long total) { return (int)((total + 255) / 256); }

extern "C" void kernel_launch(void* const* d_in, const int* in_sizes, int n_in,
                              void* d_out, int out_size, void* d_ws, size_t ws_size,
                              hipStream_t stream) {
    const float* x    = (const float*)d_in[0];
    const int*   ei   = (const int*)d_in[1];   // [2, NEDGES]
    const float* W1   = (const float*)d_in[2];
    const float* as1w = (const float*)d_in[3];
    const float* ad1w = (const float*)d_in[4];
    const float* b1   = (const float*)d_in[5];
    const float* W2   = (const float*)d_in[6];
    const float* as2w = (const float*)d_in[7];
    const float* ad2w = (const float*)d_in[8];
    const float* b2   = (const float*)d_in[9];
    float* out = (float*)d_out;

    float* ws = (float*)d_ws;
    long o = 0;
    float* h1     = ws + o; o += (long)NNODES * 128;   // layer-1 features; h2 aliases this
    float* x2     = ws + o; o += (long)NNODES * 128;   // layer-1 output / layer-2 input
    float* a_src1 = ws + o; o += (long)NNODES * 4;
    float* a_dst1 = ws + o; o += (long)NNODES * 4;
    float* a_src2 = ws + o; o += (long)NNODES;
    float* a_dst2 = ws + o; o += (long)NNODES;
    int* counts = (int*)(ws + o); o += NNODES;
    int* offs   = (int*)(ws + o); o += NNODES;
    int* cursor = (int*)(ws + o); o += NNODES;
    int* bsums  = (int*)(ws + o); o += 256;
    int* ssrc   = (int*)(ws + o); o += NEDGES;
    float* h2 = h1;   // reuse: h1 dead after layer-1 gather

    const int NB = (NNODES + 255) / 256;   // scan blocks (196)

    // ---- CSR build (dst-sorted src list) ----
    hipMemsetAsync(counts, 0, sizeof(int) * NNODES, stream);
    hist_kernel<<<nblk(NEDGES), 256, 0, stream>>>(ei, counts);
    scan1_kernel<<<NB, 256, 0, stream>>>(counts, offs, bsums, NNODES);
    scan2_kernel<<<1, 256, 0, stream>>>(bsums, NB);
    scan3_kernel<<<NB, 256, 0, stream>>>(offs, bsums, cursor, NNODES);
    scatter_kernel<<<nblk(NEDGES), 256, 0, stream>>>(ei, cursor, ssrc);

    // ---- layer 1 ----
    gemm_kernel<128><<<(NNODES + 31) / 32, 256, 0, stream>>>(x, W1, h1, NNODES);
    att_dot_kernel<4, 32><<<nblk((long)NNODES * 4), 256, 0, stream>>>(h1, as1w, ad1w, a_src1, a_dst1, NNODES);
    gather_kernel<4, 128, 1><<<nblk((long)NNODES * 64), 256, 0, stream>>>(
        ssrc, offs, cursor, a_src1, a_dst1, h1, b1, x2, NNODES);

    // ---- layer 2 ----
    gemm_kernel<64><<<(NNODES + 63) / 64, 256, 0, stream>>>(x2, W2, h2, NNODES);
    att_dot_kernel<1, 64><<<nblk((long)NNODES), 256, 0, stream>>>(h2, as2w, ad2w, a_src2, a_dst2, NNODES);
    gather_kernel<1, 64, 0><<<nblk((long)NNODES * 64), 256, 0, stream>>>(
        ssrc, offs, cursor, a_src2, a_dst2, h2, b2, out, NNODES);
}

// Round 4
// 269.622 us; speedup vs baseline: 9.2902x; 1.1625x over previous
//
#include <hip/hip_runtime.h>

#define NNODES 50000
#define NEDGES 800000
#define NSLOPE 0.2f

__device__ __forceinline__ float lrelu(float x) { return x > 0.f ? x : NSLOPE * x; }

// ---------------- fused GEMM + attention-dot ----------------
// A[nrows,128] @ W[128,NCOL] -> H[nrows,NCOL]; also a_src/a_dst[n,HEADS].
// Block: 64 rows, K=128 staged once in LDS (padded rows). 256 threads.
template<int NCOL, int HEADS>
__global__ __launch_bounds__(256) void gemm_att_kernel(
    const float* __restrict__ A, const float* __restrict__ W,
    const float* __restrict__ atts, const float* __restrict__ attd,
    float* __restrict__ H, float* __restrict__ as_, float* __restrict__ ad_,
    int nrows) {
    constexpr int LG = NCOL / 4;        // lanes per row-group (32 or 16)
    constexpr int GROUPS = 256 / LG;    // 8 or 16
    constexpr int RPT = 64 / GROUPS;    // rows per thread: 8 or 4
    constexpr int CH = NCOL / HEADS;    // 32 or 64
    constexpr int HL = CH / 4;          // lanes per head (8 or 16)
    constexpr int LDAP = 132;           // padded LDS row (floats)
    __shared__ float Alds[64 * LDAP];
    int t = threadIdx.x;
    long r0 = (long)blockIdx.x * 64;
    long abase = r0 * 128;
    long alimit = (long)nrows * 128;
    // stage 64x128 A-tile (each thread: 8 x float4, contiguous source)
#pragma unroll
    for (int i = 0; i < 8; i++) {
        int off = i * 1024 + t * 4;     // float index in tile
        float4 v = make_float4(0.f, 0.f, 0.f, 0.f);
        if (abase + off < alimit) v = *(const float4*)&A[abase + off];
        int row = off >> 7, col = off & 127;
        *(float4*)&Alds[row * LDAP + col] = v;
    }
    __syncthreads();

    int l = t % LG, g = t / LG;
    int c = l * 4;
    int rb = g * RPT;
    float4 acc[RPT];
#pragma unroll
    for (int i = 0; i < RPT; i++) acc[i] = make_float4(0.f, 0.f, 0.f, 0.f);

    for (int k0 = 0; k0 < 128; k0 += 4) {
        float4 w0 = *(const float4*)&W[(k0 + 0) * NCOL + c];
        float4 w1 = *(const float4*)&W[(k0 + 1) * NCOL + c];
        float4 w2 = *(const float4*)&W[(k0 + 2) * NCOL + c];
        float4 w3 = *(const float4*)&W[(k0 + 3) * NCOL + c];
#pragma unroll
        for (int i = 0; i < RPT; i++) {
            float4 a = *(const float4*)&Alds[(rb + i) * LDAP + k0];
            acc[i].x += a.x * w0.x + a.y * w1.x + a.z * w2.x + a.w * w3.x;
            acc[i].y += a.x * w0.y + a.y * w1.y + a.z * w2.y + a.w * w3.y;
            acc[i].z += a.x * w0.z + a.y * w1.z + a.z * w2.z + a.w * w3.z;
            acc[i].w += a.x * w0.w + a.y * w1.w + a.z * w2.w + a.w * w3.w;
        }
    }

    // epilogue: H store + fused attention dots (shfl-reduce per head)
    float4 asw = *(const float4*)&atts[c];
    float4 adw = *(const float4*)&attd[c];
#pragma unroll
    for (int i = 0; i < RPT; i++) {
        long row = r0 + rb + i;
        float ps = acc[i].x * asw.x + acc[i].y * asw.y + acc[i].z * asw.z + acc[i].w * asw.w;
        float pd = acc[i].x * adw.x + acc[i].y * adw.y + acc[i].z * adw.z + acc[i].w * adw.w;
#pragma unroll
        for (int m = 1; m < HL; m <<= 1) {
            ps += __shfl_xor(ps, m);
            pd += __shfl_xor(pd, m);
        }
        if (row < nrows) {
            *(float4*)&H[row * NCOL + c] = acc[i];
            if ((l & (HL - 1)) == 0) {
                int h = c / CH;
                as_[row * HEADS + h] = ps;
                ad_[row * HEADS + h] = pd;
            }
        }
    }
}

// ---------------- CSR build: histogram -> scan -> scatter ----------------
__global__ void hist_kernel(const int* __restrict__ ei, int* __restrict__ counts) {
    int e = blockIdx.x * 256 + threadIdx.x;
    if (e >= NEDGES) return;
    atomicAdd(&counts[ei[NEDGES + e]], 1);
}

__global__ void scan1_kernel(const int* __restrict__ counts, int* __restrict__ offs,
                             int* __restrict__ bsums, int n) {
    __shared__ int tmp[256];
    int i = blockIdx.x * 256 + threadIdx.x;
    int v = (i < n) ? counts[i] : 0;
    tmp[threadIdx.x] = v;
    __syncthreads();
    for (int off = 1; off < 256; off <<= 1) {
        int t = (threadIdx.x >= off) ? tmp[threadIdx.x - off] : 0;
        __syncthreads();
        tmp[threadIdx.x] += t;
        __syncthreads();
    }
    if (i < n) offs[i] = tmp[threadIdx.x] - v;   // exclusive within block
    if (threadIdx.x == 255) bsums[blockIdx.x] = tmp[255];
}

__global__ void scan2_kernel(int* __restrict__ bsums, int nb) {
    __shared__ int tmp[256];
    int v = (threadIdx.x < nb) ? bsums[threadIdx.x] : 0;
    tmp[threadIdx.x] = v;
    __syncthreads();
    for (int off = 1; off < 256; off <<= 1) {
        int t = (threadIdx.x >= off) ? tmp[threadIdx.x - off] : 0;
        __syncthreads();
        tmp[threadIdx.x] += t;
        __syncthreads();
    }
    if (threadIdx.x < nb) bsums[threadIdx.x] = tmp[threadIdx.x] - v;  // exclusive
}

__global__ void scan3_kernel(int* __restrict__ offs, const int* __restrict__ bsums,
                             int* __restrict__ cursor, int n) {
    int i = blockIdx.x * 256 + threadIdx.x;
    if (i >= n) return;
    int o = offs[i] + bsums[blockIdx.x];
    offs[i] = o;
    cursor[i] = o;
}

__global__ void scatter_kernel(const int* __restrict__ ei, int* __restrict__ cursor,
                               int* __restrict__ ssrc) {
    int e = blockIdx.x * 256 + threadIdx.x;
    if (e >= NEDGES) return;
    int s = ei[e], d = ei[NEDGES + e];
    int pos = atomicAdd(&cursor[d], 1);
    ssrc[pos] = s;
}

// ---------------- gather: one wave per dst node ----------------
template<int HEADS, int NCOL, int LRELU>
__global__ void gather_kernel(const int* __restrict__ ssrc, const int* __restrict__ offs,
                              const int* __restrict__ ends, const float* __restrict__ as_,
                              const float* __restrict__ ad_, const float* __restrict__ H,
                              const float* __restrict__ bias, float* __restrict__ out, int n) {
    constexpr int VPL = NCOL / 64;   // floats per lane: 2 for NCOL=128, 1 for NCOL=64
    int wave = (blockIdx.x * blockDim.x + threadIdx.x) >> 6;
    if (wave >= n) return;
    int lane = threadIdx.x & 63;
    int d = wave;
    int c = lane * VPL;
    int h = (HEADS == 1) ? 0 : (c * HEADS / NCOL);
    float acc0 = 0.f, acc1 = 0.f, den = 0.f;
    float ad_d = ad_[d * HEADS + h];
    int start = offs[d], end = ends[d];

    for (int base = start; base < end; base += 64) {
        int m = end - base; if (m > 64) m = 64;
        int sv = (lane < m) ? ssrc[base + lane] : 0;
        int i = 0;
        for (; i + 8 <= m; i += 8) {
            int s0 = __shfl(sv, i + 0), s1 = __shfl(sv, i + 1);
            int s2 = __shfl(sv, i + 2), s3 = __shfl(sv, i + 3);
            int s4 = __shfl(sv, i + 4), s5 = __shfl(sv, i + 5);
            int s6 = __shfl(sv, i + 6), s7 = __shfl(sv, i + 7);
            float w0 = __expf(lrelu(as_[s0 * HEADS + h] + ad_d));
            float w1 = __expf(lrelu(as_[s1 * HEADS + h] + ad_d));
            float w2 = __expf(lrelu(as_[s2 * HEADS + h] + ad_d));
            float w3 = __expf(lrelu(as_[s3 * HEADS + h] + ad_d));
            float w4 = __expf(lrelu(as_[s4 * HEADS + h] + ad_d));
            float w5 = __expf(lrelu(as_[s5 * HEADS + h] + ad_d));
            float w6 = __expf(lrelu(as_[s6 * HEADS + h] + ad_d));
            float w7 = __expf(lrelu(as_[s7 * HEADS + h] + ad_d));
            den += ((w0 + w1) + (w2 + w3)) + ((w4 + w5) + (w6 + w7));
            if (VPL == 2) {
                float2 v0 = *(const float2*)&H[(long)s0 * NCOL + c];
                float2 v1 = *(const float2*)&H[(long)s1 * NCOL + c];
                float2 v2 = *(const float2*)&H[(long)s2 * NCOL + c];
                float2 v3 = *(const float2*)&H[(long)s3 * NCOL + c];
                float2 v4 = *(const float2*)&H[(long)s4 * NCOL + c];
                float2 v5 = *(const float2*)&H[(long)s5 * NCOL + c];
                float2 v6 = *(const float2*)&H[(long)s6 * NCOL + c];
                float2 v7 = *(const float2*)&H[(long)s7 * NCOL + c];
                acc0 += ((w0 * v0.x + w1 * v1.x) + (w2 * v2.x + w3 * v3.x))
                      + ((w4 * v4.x + w5 * v5.x) + (w6 * v6.x + w7 * v7.x));
                acc1 += ((w0 * v0.y + w1 * v1.y) + (w2 * v2.y + w3 * v3.y))
                      + ((w4 * v4.y + w5 * v5.y) + (w6 * v6.y + w7 * v7.y));
            } else {
                float v0 = H[(long)s0 * NCOL + c], v1 = H[(long)s1 * NCOL + c];
                float v2 = H[(long)s2 * NCOL + c], v3 = H[(long)s3 * NCOL + c];
                float v4 = H[(long)s4 * NCOL + c], v5 = H[(long)s5 * NCOL + c];
                float v6 = H[(long)s6 * NCOL + c], v7 = H[(long)s7 * NCOL + c];
                acc0 += ((w0 * v0 + w1 * v1) + (w2 * v2 + w3 * v3))
                      + ((w4 * v4 + w5 * v5) + (w6 * v6 + w7 * v7));
            }
        }
        for (; i < m; i++) {
            int s = __shfl(sv, i);
            float w = __expf(lrelu(as_[s * HEADS + h] + ad_d));
            den += w;
            if (VPL == 2) {
                float2 hv = *(const float2*)&H[(long)s * NCOL + c];
                acc0 += w * hv.x; acc1 += w * hv.y;
            } else {
                acc0 += w * H[(long)s * NCOL + c];
            }
        }
    }
    {   // self loop
        float w = __expf(lrelu(as_[d * HEADS + h] + ad_d));
        den += w;
        if (VPL == 2) {
            float2 hv = *(const float2*)&H[(long)d * NCOL + c];
            acc0 += w * hv.x; acc1 += w * hv.y;
        } else {
            acc0 += w * H[(long)d * NCOL + c];
        }
    }
    float inv = 1.f / (den + 1e-16f);
    if (VPL == 2) {
        float r0 = acc0 * inv + bias[c];
        float r1 = acc1 * inv + bias[c + 1];
        if (LRELU) { r0 = lrelu(r0); r1 = lrelu(r1); }
        *(float2*)&out[(long)d * NCOL + c] = make_float2(r0, r1);
    } else {
        float r0 = acc0 * inv + bias[c];
        if (LRELU) r0 = lrelu(r0);
        out[(long)d * NCOL + c] = r0;
    }
}

static inline int nblk(long total) { return (int)((total + 255) / 256); }

extern "C" void kernel_launch(void* const* d_in, const int* in_sizes, int n_in,
                              void* d_out, int out_size, void* d_ws, size_t ws_size,
                              hipStream_t stream) {
    const float* x    = (const float*)d_in[0];
    const int*   ei   = (const int*)d_in[1];   // [2, NEDGES]
    const float* W1   = (const float*)d_in[2];
    const float* as1w = (const float*)d_in[3];
    const float* ad1w = (const float*)d_in[4];
    const float* b1   = (const float*)d_in[5];
    const float* W2   = (const float*)d_in[6];
    const float* as2w = (const float*)d_in[7];
    const float* ad2w = (const float*)d_in[8];
    const float* b2   = (const float*)d_in[9];
    float* out = (float*)d_out;

    float* ws = (float*)d_ws;
    long o = 0;
    float* h1     = ws + o; o += (long)NNODES * 128;   // layer-1 features; h2 aliases this
    float* x2     = ws + o; o += (long)NNODES * 128;   // layer-1 output / layer-2 input
    float* a_src1 = ws + o; o += (long)NNODES * 4;
    float* a_dst1 = ws + o; o += (long)NNODES * 4;
    float* a_src2 = ws + o; o += (long)NNODES;
    float* a_dst2 = ws + o; o += (long)NNODES;
    int* counts = (int*)(ws + o); o += NNODES;
    int* offs   = (int*)(ws + o); o += NNODES;
    int* cursor = (int*)(ws + o); o += NNODES;
    int* bsums  = (int*)(ws + o); o += 256;
    int* ssrc   = (int*)(ws + o); o += NEDGES;
    float* h2 = h1;   // reuse: h1 dead after layer-1 gather

    const int NB = (NNODES + 255) / 256;   // scan blocks (196)
    const int GB = (NNODES + 63) / 64;     // gemm blocks (782)

    // ---- CSR build (dst-sorted src list) ----
    hipMemsetAsync(counts, 0, sizeof(int) * NNODES, stream);
    hist_kernel<<<nblk(NEDGES), 256, 0, stream>>>(ei, counts);
    scan1_kernel<<<NB, 256, 0, stream>>>(counts, offs, bsums, NNODES);
    scan2_kernel<<<1, 256, 0, stream>>>(bsums, NB);
    scan3_kernel<<<NB, 256, 0, stream>>>(offs, bsums, cursor, NNODES);
    scatter_kernel<<<nblk(NEDGES), 256, 0, stream>>>(ei, cursor, ssrc);

    // ---- layer 1 ----
    gemm_att_kernel<128, 4><<<GB, 256, 0, stream>>>(x, W1, as1w, ad1w, h1, a_src1, a_dst1, NNODES);
    gather_kernel<4, 128, 1><<<nblk((long)NNODES * 64), 256, 0, stream>>>(
        ssrc, offs, cursor, a_src1, a_dst1, h1, b1, x2, NNODES);

    // ---- layer 2 ----
    gemm_att_kernel<64, 1><<<GB, 256, 0, stream>>>(x2, W2, as2w, ad2w, h2, a_src2, a_dst2, NNODES);
    gather_kernel<1, 64, 0><<<nblk((long)NNODES * 64), 256, 0, stream>>>(
        ssrc, offs, cursor, a_src2, a_dst2, h2, b2, out, NNODES);
}

// Round 5
// 265.165 us; speedup vs baseline: 9.4464x; 1.0168x over previous
//
#include <hip/hip_runtime.h>

#define NNODES 50000
#define NEDGES 800000
#define NSLOPE 0.2f

__device__ __forceinline__ float lrelu(float x) { return x > 0.f ? x : NSLOPE * x; }

// ---------------- fused GEMM + attention-dot ----------------
// A[nrows,128] @ W[128,NCOL] -> H[nrows,NCOL]; also a_src/a_dst[n,HEADS].
// Block: 64 rows, K=128 staged once in LDS (padded rows). 256 threads.
template<int NCOL, int HEADS>
__global__ __launch_bounds__(256) void gemm_att_kernel(
    const float* __restrict__ A, const float* __restrict__ W,
    const float* __restrict__ atts, const float* __restrict__ attd,
    float* __restrict__ H, float* __restrict__ as_, float* __restrict__ ad_,
    int nrows) {
    constexpr int LG = NCOL / 4;        // lanes per row-group (32 or 16)
    constexpr int GROUPS = 256 / LG;    // 8 or 16
    constexpr int RPT = 64 / GROUPS;    // rows per thread: 8 or 4
    constexpr int CH = NCOL / HEADS;    // 32 or 64
    constexpr int HL = CH / 4;          // lanes per head (8 or 16)
    constexpr int LDAP = 132;           // padded LDS row (floats)
    __shared__ float Alds[64 * LDAP];
    int t = threadIdx.x;
    long r0 = (long)blockIdx.x * 64;
    long abase = r0 * 128;
    long alimit = (long)nrows * 128;
    // stage 64x128 A-tile (each thread: 8 x float4, contiguous source)
#pragma unroll
    for (int i = 0; i < 8; i++) {
        int off = i * 1024 + t * 4;     // float index in tile
        float4 v = make_float4(0.f, 0.f, 0.f, 0.f);
        if (abase + off < alimit) v = *(const float4*)&A[abase + off];
        int row = off >> 7, col = off & 127;
        *(float4*)&Alds[row * LDAP + col] = v;
    }
    __syncthreads();

    int l = t % LG, g = t / LG;
    int c = l * 4;
    int rb = g * RPT;
    float4 acc[RPT];
#pragma unroll
    for (int i = 0; i < RPT; i++) acc[i] = make_float4(0.f, 0.f, 0.f, 0.f);

    for (int k0 = 0; k0 < 128; k0 += 4) {
        float4 w0 = *(const float4*)&W[(k0 + 0) * NCOL + c];
        float4 w1 = *(const float4*)&W[(k0 + 1) * NCOL + c];
        float4 w2 = *(const float4*)&W[(k0 + 2) * NCOL + c];
        float4 w3 = *(const float4*)&W[(k0 + 3) * NCOL + c];
#pragma unroll
        for (int i = 0; i < RPT; i++) {
            float4 a = *(const float4*)&Alds[(rb + i) * LDAP + k0];
            acc[i].x += a.x * w0.x + a.y * w1.x + a.z * w2.x + a.w * w3.x;
            acc[i].y += a.x * w0.y + a.y * w1.y + a.z * w2.y + a.w * w3.y;
            acc[i].z += a.x * w0.z + a.y * w1.z + a.z * w2.z + a.w * w3.z;
            acc[i].w += a.x * w0.w + a.y * w1.w + a.z * w2.w + a.w * w3.w;
        }
    }

    // epilogue: H store + fused attention dots (shfl-reduce per head)
    float4 asw = *(const float4*)&atts[c];
    float4 adw = *(const float4*)&attd[c];
#pragma unroll
    for (int i = 0; i < RPT; i++) {
        long row = r0 + rb + i;
        float ps = acc[i].x * asw.x + acc[i].y * asw.y + acc[i].z * asw.z + acc[i].w * asw.w;
        float pd = acc[i].x * adw.x + acc[i].y * adw.y + acc[i].z * adw.z + acc[i].w * adw.w;
#pragma unroll
        for (int m = 1; m < HL; m <<= 1) {
            ps += __shfl_xor(ps, m);
            pd += __shfl_xor(pd, m);
        }
        if (row < nrows) {
            *(float4*)&H[row * NCOL + c] = acc[i];
            if ((l & (HL - 1)) == 0) {
                int h = c / CH;
                as_[row * HEADS + h] = ps;
                ad_[row * HEADS + h] = pd;
            }
        }
    }
}

// ---------------- CSR build: histogram -> scan -> scatter ----------------
__global__ void hist_kernel(const int* __restrict__ ei, int* __restrict__ counts) {
    int e = blockIdx.x * 256 + threadIdx.x;
    if (e >= NEDGES) return;
    atomicAdd(&counts[ei[NEDGES + e]], 1);
}

__global__ void scan1_kernel(const int* __restrict__ counts, int* __restrict__ offs,
                             int* __restrict__ bsums, int n) {
    __shared__ int tmp[256];
    int i = blockIdx.x * 256 + threadIdx.x;
    int v = (i < n) ? counts[i] : 0;
    tmp[threadIdx.x] = v;
    __syncthreads();
    for (int off = 1; off < 256; off <<= 1) {
        int t = (threadIdx.x >= off) ? tmp[threadIdx.x - off] : 0;
        __syncthreads();
        tmp[threadIdx.x] += t;
        __syncthreads();
    }
    if (i < n) offs[i] = tmp[threadIdx.x] - v;   // exclusive within block
    if (threadIdx.x == 255) bsums[blockIdx.x] = tmp[255];
}

__global__ void scan2_kernel(int* __restrict__ bsums, int nb) {
    __shared__ int tmp[256];
    int v = (threadIdx.x < nb) ? bsums[threadIdx.x] : 0;
    tmp[threadIdx.x] = v;
    __syncthreads();
    for (int off = 1; off < 256; off <<= 1) {
        int t = (threadIdx.x >= off) ? tmp[threadIdx.x - off] : 0;
        __syncthreads();
        tmp[threadIdx.x] += t;
        __syncthreads();
    }
    if (threadIdx.x < nb) bsums[threadIdx.x] = tmp[threadIdx.x] - v;  // exclusive
}

__global__ void scan3_kernel(int* __restrict__ offs, const int* __restrict__ bsums,
                             int* __restrict__ cursor, int n) {
    int i = blockIdx.x * 256 + threadIdx.x;
    if (i >= n) return;
    int o = offs[i] + bsums[blockIdx.x];
    offs[i] = o;
    cursor[i] = o;
}

__global__ void scatter_kernel(const int* __restrict__ ei, int* __restrict__ cursor,
                               int* __restrict__ ssrc) {
    int e = blockIdx.x * 256 + threadIdx.x;
    if (e >= NEDGES) return;
    int s = ei[e], d = ei[NEDGES + e];
    int pos = atomicAdd(&cursor[d], 1);
    ssrc[pos] = s;
}

// ---------------- gather: one wave per dst node ----------------
// Edge-parallel weight phase: each lane computes w for one (edge,head) of the
// chunk; consume loop is just 2 shfl + row load + FMA per edge.
template<int HEADS, int NCOL, int LRELU>
__global__ void gather_kernel(const int* __restrict__ ssrc, const int* __restrict__ offs,
                              const int* __restrict__ ends, const float* __restrict__ as_,
                              const float* __restrict__ ad_, const float* __restrict__ H,
                              const float* __restrict__ bias, float* __restrict__ out, int n) {
    constexpr int VPL = NCOL / 64;      // floats per lane: 2 (L1) or 1 (L2)
    constexpr int CHUNK = 64 / HEADS;   // edges per chunk: 16 (L1) or 64 (L2)
    int wave = (blockIdx.x * blockDim.x + threadIdx.x) >> 6;
    if (wave >= n) return;
    int lane = threadIdx.x & 63;
    int d = wave;
    int c = lane * VPL;
    int h = (HEADS == 1) ? 0 : (lane / CHUNK);     // consuming head == producing head
    int sb = h * CHUNK;                            // shfl source base for w
    float acc0 = 0.f, acc1 = 0.f, den = 0.f;
    float ad_d = ad_[d * HEADS + h];
    int start = offs[d], end = ends[d];

    for (int base = start; base < end; base += CHUNK) {
        int m = end - base; if (m > CHUNK) m = CHUNK;
        int eidx = (HEADS == 1) ? lane : (lane & (CHUNK - 1));
        int sv = 0; float wv = 0.f;
        if (eidx < m) {
            sv = ssrc[base + eidx];
            wv = __expf(lrelu(as_[sv * HEADS + h] + ad_d));
        }
        int i = 0;
        for (; i + 8 <= m; i += 8) {
            int s0 = __shfl(sv, i + 0), s1 = __shfl(sv, i + 1);
            int s2 = __shfl(sv, i + 2), s3 = __shfl(sv, i + 3);
            int s4 = __shfl(sv, i + 4), s5 = __shfl(sv, i + 5);
            int s6 = __shfl(sv, i + 6), s7 = __shfl(sv, i + 7);
            float w0 = __shfl(wv, sb + i + 0), w1 = __shfl(wv, sb + i + 1);
            float w2 = __shfl(wv, sb + i + 2), w3 = __shfl(wv, sb + i + 3);
            float w4 = __shfl(wv, sb + i + 4), w5 = __shfl(wv, sb + i + 5);
            float w6 = __shfl(wv, sb + i + 6), w7 = __shfl(wv, sb + i + 7);
            den += ((w0 + w1) + (w2 + w3)) + ((w4 + w5) + (w6 + w7));
            if (VPL == 2) {
                float2 v0 = *(const float2*)&H[(long)s0 * NCOL + c];
                float2 v1 = *(const float2*)&H[(long)s1 * NCOL + c];
                float2 v2 = *(const float2*)&H[(long)s2 * NCOL + c];
                float2 v3 = *(const float2*)&H[(long)s3 * NCOL + c];
                float2 v4 = *(const float2*)&H[(long)s4 * NCOL + c];
                float2 v5 = *(const float2*)&H[(long)s5 * NCOL + c];
                float2 v6 = *(const float2*)&H[(long)s6 * NCOL + c];
                float2 v7 = *(const float2*)&H[(long)s7 * NCOL + c];
                acc0 += ((w0 * v0.x + w1 * v1.x) + (w2 * v2.x + w3 * v3.x))
                      + ((w4 * v4.x + w5 * v5.x) + (w6 * v6.x + w7 * v7.x));
                acc1 += ((w0 * v0.y + w1 * v1.y) + (w2 * v2.y + w3 * v3.y))
                      + ((w4 * v4.y + w5 * v5.y) + (w6 * v6.y + w7 * v7.y));
            } else {
                float v0 = H[(long)s0 * NCOL + c], v1 = H[(long)s1 * NCOL + c];
                float v2 = H[(long)s2 * NCOL + c], v3 = H[(long)s3 * NCOL + c];
                float v4 = H[(long)s4 * NCOL + c], v5 = H[(long)s5 * NCOL + c];
                float v6 = H[(long)s6 * NCOL + c], v7 = H[(long)s7 * NCOL + c];
                acc0 += ((w0 * v0 + w1 * v1) + (w2 * v2 + w3 * v3))
                      + ((w4 * v4 + w5 * v5) + (w6 * v6 + w7 * v7));
            }
        }
        for (; i < m; i++) {
            int s = __shfl(sv, i);
            float w = __shfl(wv, sb + i);
            den += w;
            if (VPL == 2) {
                float2 hv = *(const float2*)&H[(long)s * NCOL + c];
                acc0 += w * hv.x; acc1 += w * hv.y;
            } else {
                acc0 += w * H[(long)s * NCOL + c];
            }
        }
    }
    {   // self loop
        float w = __expf(lrelu(as_[d * HEADS + h] + ad_d));
        den += w;
        if (VPL == 2) {
            float2 hv = *(const float2*)&H[(long)d * NCOL + c];
            acc0 += w * hv.x; acc1 += w * hv.y;
        } else {
            acc0 += w * H[(long)d * NCOL + c];
        }
    }
    float inv = 1.f / (den + 1e-16f);
    if (VPL == 2) {
        float r0 = acc0 * inv + bias[c];
        float r1 = acc1 * inv + bias[c + 1];
        if (LRELU) { r0 = lrelu(r0); r1 = lrelu(r1); }
        *(float2*)&out[(long)d * NCOL + c] = make_float2(r0, r1);
    } else {
        float r0 = acc0 * inv + bias[c];
        if (LRELU) r0 = lrelu(r0);
        out[(long)d * NCOL + c] = r0;
    }
}

static inline int nblk(long total) { return (int)((total + 255) / 256); }

extern "C" void kernel_launch(void* const* d_in, const int* in_sizes, int n_in,
                              void* d_out, int out_size, void* d_ws, size_t ws_size,
                              hipStream_t stream) {
    const float* x    = (const float*)d_in[0];
    const int*   ei   = (const int*)d_in[1];   // [2, NEDGES]
    const float* W1   = (const float*)d_in[2];
    const float* as1w = (const float*)d_in[3];
    const float* ad1w = (const float*)d_in[4];
    const float* b1   = (const float*)d_in[5];
    const float* W2   = (const float*)d_in[6];
    const float* as2w = (const float*)d_in[7];
    const float* ad2w = (const float*)d_in[8];
    const float* b2   = (const float*)d_in[9];
    float* out = (float*)d_out;

    float* ws = (float*)d_ws;
    long o = 0;
    float* h1     = ws + o; o += (long)NNODES * 128;   // layer-1 features; h2 aliases this
    float* x2     = ws + o; o += (long)NNODES * 128;   // layer-1 output / layer-2 input
    float* a_src1 = ws + o; o += (long)NNODES * 4;
    float* a_dst1 = ws + o; o += (long)NNODES * 4;
    float* a_src2 = ws + o; o += (long)NNODES;
    float* a_dst2 = ws + o; o += (long)NNODES;
    int* counts = (int*)(ws + o); o += NNODES;
    int* offs   = (int*)(ws + o); o += NNODES;
    int* cursor = (int*)(ws + o); o += NNODES;
    int* bsums  = (int*)(ws + o); o += 256;
    int* ssrc   = (int*)(ws + o); o += NEDGES;
    float* h2 = h1;   // reuse: h1 dead after layer-1 gather

    const int NB = (NNODES + 255) / 256;   // scan blocks (196)
    const int GB = (NNODES + 63) / 64;     // gemm blocks (782)

    // ---- CSR build (dst-sorted src list) ----
    hipMemsetAsync(counts, 0, sizeof(int) * NNODES, stream);
    hist_kernel<<<nblk(NEDGES), 256, 0, stream>>>(ei, counts);
    scan1_kernel<<<NB, 256, 0, stream>>>(counts, offs, bsums, NNODES);
    scan2_kernel<<<1, 256, 0, stream>>>(bsums, NB);
    scan3_kernel<<<NB, 256, 0, stream>>>(offs, bsums, cursor, NNODES);
    scatter_kernel<<<nblk(NEDGES), 256, 0, stream>>>(ei, cursor, ssrc);

    // ---- layer 1 ----
    gemm_att_kernel<128, 4><<<GB, 256, 0, stream>>>(x, W1, as1w, ad1w, h1, a_src1, a_dst1, NNODES);
    gather_kernel<4, 128, 1><<<nblk((long)NNODES * 64), 256, 0, stream>>>(
        ssrc, offs, cursor, a_src1, a_dst1, h1, b1, x2, NNODES);

    // ---- layer 2 ----
    gemm_att_kernel<64, 1><<<GB, 256, 0, stream>>>(x2, W2, as2w, ad2w, h2, a_src2, a_dst2, NNODES);
    gather_kernel<1, 64, 0><<<nblk((long)NNODES * 64), 256, 0, stream>>>(
        ssrc, offs, cursor, a_src2, a_dst2, h2, b2, out, NNODES);
}

// Round 6
// 263.160 us; speedup vs baseline: 9.5183x; 1.0076x over previous
//
#include <hip/hip_runtime.h>

#define NNODES 50000
#define NEDGES 800000
#define NSLOPE 0.2f

__device__ __forceinline__ float lrelu(float x) { return x > 0.f ? x : NSLOPE * x; }

// ---------------- fused GEMM + attention-dot ----------------
// A[nrows,128] @ W[128,NCOL] -> H[nrows,NCOL]; also a_src/a_dst[n,HEADS].
// Block: 64 rows, K=128 staged once in LDS (padded rows). 256 threads.
template<int NCOL, int HEADS>
__global__ __launch_bounds__(256) void gemm_att_kernel(
    const float* __restrict__ A, const float* __restrict__ W,
    const float* __restrict__ atts, const float* __restrict__ attd,
    float* __restrict__ H, float* __restrict__ as_, float* __restrict__ ad_,
    int nrows) {
    constexpr int LG = NCOL / 4;        // lanes per row-group (32 or 16)
    constexpr int GROUPS = 256 / LG;    // 8 or 16
    constexpr int RPT = 64 / GROUPS;    // rows per thread: 8 or 4
    constexpr int CH = NCOL / HEADS;    // 32 or 64
    constexpr int HL = CH / 4;          // lanes per head (8 or 16)
    constexpr int LDAP = 132;           // padded LDS row (floats)
    __shared__ float Alds[64 * LDAP];
    int t = threadIdx.x;
    long r0 = (long)blockIdx.x * 64;
    long abase = r0 * 128;
    long alimit = (long)nrows * 128;
#pragma unroll
    for (int i = 0; i < 8; i++) {
        int off = i * 1024 + t * 4;     // float index in tile
        float4 v = make_float4(0.f, 0.f, 0.f, 0.f);
        if (abase + off < alimit) v = *(const float4*)&A[abase + off];
        int row = off >> 7, col = off & 127;
        *(float4*)&Alds[row * LDAP + col] = v;
    }
    __syncthreads();

    int l = t % LG, g = t / LG;
    int c = l * 4;
    int rb = g * RPT;
    float4 acc[RPT];
#pragma unroll
    for (int i = 0; i < RPT; i++) acc[i] = make_float4(0.f, 0.f, 0.f, 0.f);

    for (int k0 = 0; k0 < 128; k0 += 4) {
        float4 w0 = *(const float4*)&W[(k0 + 0) * NCOL + c];
        float4 w1 = *(const float4*)&W[(k0 + 1) * NCOL + c];
        float4 w2 = *(const float4*)&W[(k0 + 2) * NCOL + c];
        float4 w3 = *(const float4*)&W[(k0 + 3) * NCOL + c];
#pragma unroll
        for (int i = 0; i < RPT; i++) {
            float4 a = *(const float4*)&Alds[(rb + i) * LDAP + k0];
            acc[i].x += a.x * w0.x + a.y * w1.x + a.z * w2.x + a.w * w3.x;
            acc[i].y += a.x * w0.y + a.y * w1.y + a.z * w2.y + a.w * w3.y;
            acc[i].z += a.x * w0.z + a.y * w1.z + a.z * w2.z + a.w * w3.z;
            acc[i].w += a.x * w0.w + a.y * w1.w + a.z * w2.w + a.w * w3.w;
        }
    }

    float4 asw = *(const float4*)&atts[c];
    float4 adw = *(const float4*)&attd[c];
#pragma unroll
    for (int i = 0; i < RPT; i++) {
        long row = r0 + rb + i;
        float ps = acc[i].x * asw.x + acc[i].y * asw.y + acc[i].z * asw.z + acc[i].w * asw.w;
        float pd = acc[i].x * adw.x + acc[i].y * adw.y + acc[i].z * adw.z + acc[i].w * adw.w;
#pragma unroll
        for (int m = 1; m < HL; m <<= 1) {
            ps += __shfl_xor(ps, m);
            pd += __shfl_xor(pd, m);
        }
        if (row < nrows) {
            *(float4*)&H[row * NCOL + c] = acc[i];
            if ((l & (HL - 1)) == 0) {
                int h = c / CH;
                as_[row * HEADS + h] = ps;
                ad_[row * HEADS + h] = pd;
            }
        }
    }
}

// ---------------- CSR build: histogram -> scan -> scatter ----------------
__global__ void hist_kernel(const int* __restrict__ ei, int* __restrict__ counts) {
    int e = blockIdx.x * 256 + threadIdx.x;
    if (e >= NEDGES) return;
    atomicAdd(&counts[ei[NEDGES + e]], 1);
}

__global__ void scan1_kernel(const int* __restrict__ counts, int* __restrict__ offs,
                             int* __restrict__ bsums, int n) {
    __shared__ int tmp[256];
    int i = blockIdx.x * 256 + threadIdx.x;
    int v = (i < n) ? counts[i] : 0;
    tmp[threadIdx.x] = v;
    __syncthreads();
    for (int off = 1; off < 256; off <<= 1) {
        int t = (threadIdx.x >= off) ? tmp[threadIdx.x - off] : 0;
        __syncthreads();
        tmp[threadIdx.x] += t;
        __syncthreads();
    }
    if (i < n) offs[i] = tmp[threadIdx.x] - v;   // exclusive within block
    if (threadIdx.x == 255) bsums[blockIdx.x] = tmp[255];
}

__global__ void scan2_kernel(int* __restrict__ bsums, int nb) {
    __shared__ int tmp[256];
    int v = (threadIdx.x < nb) ? bsums[threadIdx.x] : 0;
    tmp[threadIdx.x] = v;
    __syncthreads();
    for (int off = 1; off < 256; off <<= 1) {
        int t = (threadIdx.x >= off) ? tmp[threadIdx.x - off] : 0;
        __syncthreads();
        tmp[threadIdx.x] += t;
        __syncthreads();
    }
    if (threadIdx.x < nb) bsums[threadIdx.x] = tmp[threadIdx.x] - v;  // exclusive
}

__global__ void scan3_kernel(int* __restrict__ offs, const int* __restrict__ bsums,
                             int* __restrict__ cursor, int n) {
    int i = blockIdx.x * 256 + threadIdx.x;
    if (i >= n) return;
    int o = offs[i] + bsums[blockIdx.x];
    offs[i] = o;
    cursor[i] = o;
}

__global__ void scatter_kernel(const int* __restrict__ ei, int* __restrict__ cursor,
                               int* __restrict__ ssrc) {
    int e = blockIdx.x * 256 + threadIdx.x;
    if (e >= NEDGES) return;
    int s = ei[e], d = ei[NEDGES + e];
    int pos = atomicAdd(&cursor[d], 1);
    ssrc[pos] = s;
}

// ---------------- gather: one wave per dst node ----------------
// float4 sub-wave rows: one VMEM instruction covers EPI edges.
// Edge-parallel weights incl. denominator; sv prefetch one chunk ahead.
template<int HEADS, int NCOL, int LRELU>
__global__ __launch_bounds__(256) void gather_kernel(
    const int* __restrict__ ssrc, const int* __restrict__ offs,
    const int* __restrict__ ends, const float* __restrict__ as_,
    const float* __restrict__ ad_, const float* __restrict__ H,
    const float* __restrict__ bias, float* __restrict__ out, int n) {
    constexpr int CHUNK = 64 / HEADS;   // edges per chunk: 16 (L1) or 64 (L2)
    constexpr int LPE = NCOL / 4;       // lanes per edge row (float4): 32 or 16
    constexpr int EPI = 64 / LPE;       // edges per VMEM instr: 2 or 4
    int wave = (blockIdx.x * blockDim.x + threadIdx.x) >> 6;
    if (wave >= n) return;
    int lane = threadIdx.x & 63;
    int d = wave;
    int sub = lane / LPE;               // sub-wave id (which edge of the group)
    int c = (lane % LPE) * 4;           // channel base for this lane
    int hc = (HEADS == 1) ? 0 : (c >> 5);        // consuming head
    int pe = lane % CHUNK;              // producer: edge slot in chunk
    int ph = (HEADS == 1) ? 0 : (lane / CHUNK);  // producer: head
    float ad_p = ad_[d * HEADS + ph];
    float4 acc = make_float4(0.f, 0.f, 0.f, 0.f);
    float dsum = 0.f;
    int start = offs[d], end = ends[d];

    int base = start;
    int m = end - base; if (m > CHUNK) m = CHUNK;
    int sv = 0; float wv = 0.f;
    if (m > 0) {
        if (pe < m) {
            sv = ssrc[base + pe];
            wv = __expf(lrelu(as_[sv * HEADS + ph] + ad_p));
        }
        dsum += wv;
    }
    while (m > 0) {
        int nbase = base + CHUNK;
        int nm = end - nbase; if (nm > CHUNK) nm = CHUNK;
        int svn = 0;
        if (nm > 0 && pe < nm) svn = ssrc[nbase + pe];   // prefetch next chunk
        // consume current chunk: groups of 4 VMEM (= 4*EPI edges)
        int i = 0;
        for (; i + 4 * EPI <= m; i += 4 * EPI) {
            int i0 = i + sub, i1 = i + EPI + sub, i2 = i + 2 * EPI + sub, i3 = i + 3 * EPI + sub;
            int s0 = __shfl(sv, hc * CHUNK + i0);
            int s1 = __shfl(sv, hc * CHUNK + i1);
            int s2 = __shfl(sv, hc * CHUNK + i2);
            int s3 = __shfl(sv, hc * CHUNK + i3);
            float w0 = __shfl(wv, hc * CHUNK + i0);
            float w1 = __shfl(wv, hc * CHUNK + i1);
            float w2 = __shfl(wv, hc * CHUNK + i2);
            float w3 = __shfl(wv, hc * CHUNK + i3);
            float4 v0 = *(const float4*)&H[(long)s0 * NCOL + c];
            float4 v1 = *(const float4*)&H[(long)s1 * NCOL + c];
            float4 v2 = *(const float4*)&H[(long)s2 * NCOL + c];
            float4 v3 = *(const float4*)&H[(long)s3 * NCOL + c];
            acc.x += (w0 * v0.x + w1 * v1.x) + (w2 * v2.x + w3 * v3.x);
            acc.y += (w0 * v0.y + w1 * v1.y) + (w2 * v2.y + w3 * v3.y);
            acc.z += (w0 * v0.z + w1 * v1.z) + (w2 * v2.z + w3 * v3.z);
            acc.w += (w0 * v0.w + w1 * v1.w) + (w2 * v2.w + w3 * v3.w);
        }
        for (; i < m; i += EPI) {
            int idx = i + sub;
            int cl = (idx < m) ? idx : (m - 1);
            int s = __shfl(sv, hc * CHUNK + cl);
            float w = __shfl(wv, hc * CHUNK + cl);
            if (idx >= m) w = 0.f;
            float4 v = *(const float4*)&H[(long)s * NCOL + c];
            acc.x += w * v.x; acc.y += w * v.y; acc.z += w * v.z; acc.w += w * v.w;
        }
        if (nm <= 0) break;
        float wvn = 0.f;
        if (pe < nm) wvn = __expf(lrelu(as_[svn * HEADS + ph] + ad_p));
        dsum += wvn;
        sv = svn; wv = wvn; m = nm; base = nbase;
    }

    // denominator reduction (producer layout)
    if (HEADS == 1) {
#pragma unroll
        for (int msk = 1; msk < 64; msk <<= 1) dsum += __shfl_xor(dsum, msk);
    } else {
#pragma unroll
        for (int msk = 1; msk < 16; msk <<= 1) dsum += __shfl_xor(dsum, msk);
        dsum = __shfl(dsum, hc * CHUNK);    // den for consuming head
    }
    // fold accumulator across sub-wave groups
    if (EPI == 4) {
        acc.x += __shfl_xor(acc.x, 16); acc.y += __shfl_xor(acc.y, 16);
        acc.z += __shfl_xor(acc.z, 16); acc.w += __shfl_xor(acc.w, 16);
    }
    acc.x += __shfl_xor(acc.x, 32); acc.y += __shfl_xor(acc.y, 32);
    acc.z += __shfl_xor(acc.z, 32); acc.w += __shfl_xor(acc.w, 32);
    // self loop (after fold: added exactly once per channel)
    {
        float wself = __expf(lrelu(as_[d * HEADS + hc] + ad_[d * HEADS + hc]));
        dsum += wself;
        float4 vs = *(const float4*)&H[(long)d * NCOL + c];
        acc.x += wself * vs.x; acc.y += wself * vs.y;
        acc.z += wself * vs.z; acc.w += wself * vs.w;
    }
    float inv = 1.f / (dsum + 1e-16f);
    float4 bv = *(const float4*)&bias[c];
    float r0 = acc.x * inv + bv.x, r1 = acc.y * inv + bv.y;
    float r2 = acc.z * inv + bv.z, r3 = acc.w * inv + bv.w;
    if (LRELU) { r0 = lrelu(r0); r1 = lrelu(r1); r2 = lrelu(r2); r3 = lrelu(r3); }
    if (lane < LPE) *(float4*)&out[(long)d * NCOL + c] = make_float4(r0, r1, r2, r3);
}

static inline int nblk(long total) { return (int)((total + 255) / 256); }

extern "C" void kernel_launch(void* const* d_in, const int* in_sizes, int n_in,
                              void* d_out, int out_size, void* d_ws, size_t ws_size,
                              hipStream_t stream) {
    const float* x    = (const float*)d_in[0];
    const int*   ei   = (const int*)d_in[1];   // [2, NEDGES]
    const float* W1   = (const float*)d_in[2];
    const float* as1w = (const float*)d_in[3];
    const float* ad1w = (const float*)d_in[4];
    const float* b1   = (const float*)d_in[5];
    const float* W2   = (const float*)d_in[6];
    const float* as2w = (const float*)d_in[7];
    const float* ad2w = (const float*)d_in[8];
    const float* b2   = (const float*)d_in[9];
    float* out = (float*)d_out;

    float* ws = (float*)d_ws;
    long o = 0;
    float* h1     = ws + o; o += (long)NNODES * 128;   // layer-1 features; h2 aliases this
    float* x2     = ws + o; o += (long)NNODES * 128;   // layer-1 output / layer-2 input
    float* a_src1 = ws + o; o += (long)NNODES * 4;
    float* a_dst1 = ws + o; o += (long)NNODES * 4;
    float* a_src2 = ws + o; o += (long)NNODES;
    float* a_dst2 = ws + o; o += (long)NNODES;
    int* counts = (int*)(ws + o); o += NNODES;
    int* offs   = (int*)(ws + o); o += NNODES;
    int* cursor = (int*)(ws + o); o += NNODES;
    int* bsums  = (int*)(ws + o); o += 256;
    int* ssrc   = (int*)(ws + o); o += NEDGES;
    float* h2 = h1;   // reuse: h1 dead after layer-1 gather

    const int NB = (NNODES + 255) / 256;   // scan blocks (196)
    const int GB = (NNODES + 63) / 64;     // gemm blocks (782)

    // ---- CSR build (dst-sorted src list) ----
    hipMemsetAsync(counts, 0, sizeof(int) * NNODES, stream);
    hist_kernel<<<nblk(NEDGES), 256, 0, stream>>>(ei, counts);
    scan1_kernel<<<NB, 256, 0, stream>>>(counts, offs, bsums, NNODES);
    scan2_kernel<<<1, 256, 0, stream>>>(bsums, NB);
    scan3_kernel<<<NB, 256, 0, stream>>>(offs, bsums, cursor, NNODES);
    scatter_kernel<<<nblk(NEDGES), 256, 0, stream>>>(ei, cursor, ssrc);

    // ---- layer 1 ----
    gemm_att_kernel<128, 4><<<GB, 256, 0, stream>>>(x, W1, as1w, ad1w, h1, a_src1, a_dst1, NNODES);
    gather_kernel<4, 128, 1><<<nblk((long)NNODES * 64), 256, 0, stream>>>(
        ssrc, offs, cursor, a_src1, a_dst1, h1, b1, x2, NNODES);

    // ---- layer 2 ----
    gemm_att_kernel<64, 1><<<GB, 256, 0, stream>>>(x2, W2, as2w, ad2w, h2, a_src2, a_dst2, NNODES);
    gather_kernel<1, 64, 0><<<nblk((long)NNODES * 64), 256, 0, stream>>>(
        ssrc, offs, cursor, a_src2, a_dst2, h2, b2, out, NNODES);
}

// Round 7
// 239.027 us; speedup vs baseline: 10.4793x; 1.1010x over previous
//
#include <hip/hip_runtime.h>
#include <hip/hip_fp16.h>

#define NNODES 50000
#define NEDGES 800000
#define NSLOPE 0.2f

__device__ __forceinline__ float lrelu(float x) { return x > 0.f ? x : NSLOPE * x; }

// unpack 8 halves (uint4) and accumulate w * v into acc[0..7]
__device__ __forceinline__ void fma8(float* acc, uint4 v, float w) {
    __half2 p0 = *(__half2*)&v.x, p1 = *(__half2*)&v.y;
    __half2 p2 = *(__half2*)&v.z, p3 = *(__half2*)&v.w;
    float2 f;
    f = __half22float2(p0); acc[0] += w * f.x; acc[1] += w * f.y;
    f = __half22float2(p1); acc[2] += w * f.x; acc[3] += w * f.y;
    f = __half22float2(p2); acc[4] += w * f.x; acc[5] += w * f.y;
    f = __half22float2(p3); acc[6] += w * f.x; acc[7] += w * f.y;
}

// ---------------- fused GEMM + attention-dot ----------------
// A[nrows,128](fp32) @ W[128,NCOL](fp32) -> H[nrows,NCOL](fp16); a_src/a_dst fp32.
template<int NCOL, int HEADS>
__global__ __launch_bounds__(256) void gemm_att_kernel(
    const float* __restrict__ A, const float* __restrict__ W,
    const float* __restrict__ atts, const float* __restrict__ attd,
    __half* __restrict__ H, float* __restrict__ as_, float* __restrict__ ad_,
    int nrows) {
    constexpr int LG = NCOL / 4;        // lanes per row-group (32 or 16)
    constexpr int GROUPS = 256 / LG;    // 8 or 16
    constexpr int RPT = 64 / GROUPS;    // rows per thread: 8 or 4
    constexpr int CH = NCOL / HEADS;    // 32 or 64
    constexpr int HL = CH / 4;          // lanes per head (8 or 16)
    constexpr int LDAP = 132;           // padded LDS row (floats)
    __shared__ float Alds[64 * LDAP];
    int t = threadIdx.x;
    long r0 = (long)blockIdx.x * 64;
    long abase = r0 * 128;
    long alimit = (long)nrows * 128;
#pragma unroll
    for (int i = 0; i < 8; i++) {
        int off = i * 1024 + t * 4;
        float4 v = make_float4(0.f, 0.f, 0.f, 0.f);
        if (abase + off < alimit) v = *(const float4*)&A[abase + off];
        int row = off >> 7, col = off & 127;
        *(float4*)&Alds[row * LDAP + col] = v;
    }
    __syncthreads();

    int l = t % LG, g = t / LG;
    int c = l * 4;
    int rb = g * RPT;
    float4 acc[RPT];
#pragma unroll
    for (int i = 0; i < RPT; i++) acc[i] = make_float4(0.f, 0.f, 0.f, 0.f);

    for (int k0 = 0; k0 < 128; k0 += 4) {
        float4 w0 = *(const float4*)&W[(k0 + 0) * NCOL + c];
        float4 w1 = *(const float4*)&W[(k0 + 1) * NCOL + c];
        float4 w2 = *(const float4*)&W[(k0 + 2) * NCOL + c];
        float4 w3 = *(const float4*)&W[(k0 + 3) * NCOL + c];
#pragma unroll
        for (int i = 0; i < RPT; i++) {
            float4 a = *(const float4*)&Alds[(rb + i) * LDAP + k0];
            acc[i].x += a.x * w0.x + a.y * w1.x + a.z * w2.x + a.w * w3.x;
            acc[i].y += a.x * w0.y + a.y * w1.y + a.z * w2.y + a.w * w3.y;
            acc[i].z += a.x * w0.z + a.y * w1.z + a.z * w2.z + a.w * w3.z;
            acc[i].w += a.x * w0.w + a.y * w1.w + a.z * w2.w + a.w * w3.w;
        }
    }

    float4 asw = *(const float4*)&atts[c];
    float4 adw = *(const float4*)&attd[c];
#pragma unroll
    for (int i = 0; i < RPT; i++) {
        long row = r0 + rb + i;
        float ps = acc[i].x * asw.x + acc[i].y * asw.y + acc[i].z * asw.z + acc[i].w * asw.w;
        float pd = acc[i].x * adw.x + acc[i].y * adw.y + acc[i].z * adw.z + acc[i].w * adw.w;
#pragma unroll
        for (int m = 1; m < HL; m <<= 1) {
            ps += __shfl_xor(ps, m);
            pd += __shfl_xor(pd, m);
        }
        if (row < nrows) {
            __half2 p0 = __floats2half2_rn(acc[i].x, acc[i].y);
            __half2 p1 = __floats2half2_rn(acc[i].z, acc[i].w);
            uint2 pk = make_uint2(*(unsigned*)&p0, *(unsigned*)&p1);
            *(uint2*)&H[row * NCOL + c] = pk;
            if ((l & (HL - 1)) == 0) {
                int h = c / CH;
                as_[row * HEADS + h] = ps;
                ad_[row * HEADS + h] = pd;
            }
        }
    }
}

// ---------------- CSR build: histogram -> scan -> scatter ----------------
__global__ void hist_kernel(const int* __restrict__ ei, int* __restrict__ counts) {
    int e = blockIdx.x * 256 + threadIdx.x;
    if (e >= NEDGES) return;
    atomicAdd(&counts[ei[NEDGES + e]], 1);
}

__global__ void scan1_kernel(const int* __restrict__ counts, int* __restrict__ offs,
                             int* __restrict__ bsums, int n) {
    __shared__ int tmp[256];
    int i = blockIdx.x * 256 + threadIdx.x;
    int v = (i < n) ? counts[i] : 0;
    tmp[threadIdx.x] = v;
    __syncthreads();
    for (int off = 1; off < 256; off <<= 1) {
        int t = (threadIdx.x >= off) ? tmp[threadIdx.x - off] : 0;
        __syncthreads();
        tmp[threadIdx.x] += t;
        __syncthreads();
    }
    if (i < n) offs[i] = tmp[threadIdx.x] - v;
    if (threadIdx.x == 255) bsums[blockIdx.x] = tmp[255];
}

__global__ void scan2_kernel(int* __restrict__ bsums, int nb) {
    __shared__ int tmp[256];
    int v = (threadIdx.x < nb) ? bsums[threadIdx.x] : 0;
    tmp[threadIdx.x] = v;
    __syncthreads();
    for (int off = 1; off < 256; off <<= 1) {
        int t = (threadIdx.x >= off) ? tmp[threadIdx.x - off] : 0;
        __syncthreads();
        tmp[threadIdx.x] += t;
        __syncthreads();
    }
    if (threadIdx.x < nb) bsums[threadIdx.x] = tmp[threadIdx.x] - v;
}

__global__ void scan3_kernel(int* __restrict__ offs, const int* __restrict__ bsums,
                             int* __restrict__ cursor, int n) {
    int i = blockIdx.x * 256 + threadIdx.x;
    if (i >= n) return;
    int o = offs[i] + bsums[blockIdx.x];
    offs[i] = o;
    cursor[i] = o;
}

__global__ void scatter_kernel(const int* __restrict__ ei, int* __restrict__ cursor,
                               int* __restrict__ ssrc) {
    int e = blockIdx.x * 256 + threadIdx.x;
    if (e >= NEDGES) return;
    int s = ei[e], d = ei[NEDGES + e];
    int pos = atomicAdd(&cursor[d], 1);
    ssrc[pos] = s;
}

// ---------------- gather: one wave per dst node, fp16 rows ----------------
// uint4 (8 halves) per lane: L1 row=16 lanes -> 4 edges/VMEM; L2 row=8 lanes -> 8.
template<int HEADS, int NCOL, int LRELU>
__global__ __launch_bounds__(256) void gather_kernel(
    const int* __restrict__ ssrc, const int* __restrict__ offs,
    const int* __restrict__ ends, const float* __restrict__ as_,
    const float* __restrict__ ad_, const __half* __restrict__ H,
    const float* __restrict__ bias, float* __restrict__ out, int n) {
    constexpr int CHUNK = 64 / HEADS;   // edges per producer chunk: 16 (L1), 64 (L2)
    constexpr int LPE = NCOL / 8;       // lanes per row: 16 (L1), 8 (L2)
    constexpr int EPI = 64 / LPE;       // edges per VMEM instr: 4 (L1), 8 (L2)
    int wave = (blockIdx.x * blockDim.x + threadIdx.x) >> 6;
    if (wave >= n) return;
    int lane = threadIdx.x & 63;
    int d = wave;
    int sub = lane / LPE;                        // which edge of the VMEM group
    int c = (lane % LPE) * 8;                    // channel base (8 channels/lane)
    int hc = (HEADS == 1) ? 0 : (c >> 5);        // consuming head
    int SB = hc * CHUNK;                         // shfl base
    int pe = (HEADS == 1) ? lane : (lane % CHUNK);   // producer edge slot
    int ph = (HEADS == 1) ? 0 : (lane / CHUNK);      // producer head
    float ad_p = ad_[d * HEADS + ph];
    float acc[8];
#pragma unroll
    for (int i = 0; i < 8; i++) acc[i] = 0.f;
    float dsum = 0.f;
    int start = offs[d], end = ends[d];

    int base = start;
    int m = end - base; if (m > CHUNK) m = CHUNK;
    int sv = 0; float wv = 0.f;
    if (m > 0) {
        if (pe < m) {
            sv = ssrc[base + pe];
            wv = __expf(lrelu(as_[sv * HEADS + ph] + ad_p));
        }
        dsum += wv;
    }
    while (m > 0) {
        int nbase = base + CHUNK;
        int nm = end - nbase; if (nm > CHUNK) nm = CHUNK;
        int svn = 0;
        if (nm > 0 && pe < nm) svn = ssrc[nbase + pe];   // prefetch next chunk
        int i = 0;
        for (; i + 4 * EPI <= m; i += 4 * EPI) {
            int i0 = i + sub, i1 = i + EPI + sub, i2 = i + 2 * EPI + sub, i3 = i + 3 * EPI + sub;
            int s0 = __shfl(sv, SB + i0);
            int s1 = __shfl(sv, SB + i1);
            int s2 = __shfl(sv, SB + i2);
            int s3 = __shfl(sv, SB + i3);
            uint4 v0 = *(const uint4*)&H[(long)s0 * NCOL + c];
            uint4 v1 = *(const uint4*)&H[(long)s1 * NCOL + c];
            uint4 v2 = *(const uint4*)&H[(long)s2 * NCOL + c];
            uint4 v3 = *(const uint4*)&H[(long)s3 * NCOL + c];
            float w0 = __shfl(wv, SB + i0);
            float w1 = __shfl(wv, SB + i1);
            float w2 = __shfl(wv, SB + i2);
            float w3 = __shfl(wv, SB + i3);
            fma8(acc, v0, w0); fma8(acc, v1, w1);
            fma8(acc, v2, w2); fma8(acc, v3, w3);
        }
        for (; i < m; i += EPI) {
            int idx = i + sub;
            int cl = (idx < m) ? idx : (m - 1);
            int s = __shfl(sv, SB + cl);
            float w = __shfl(wv, SB + cl);
            if (idx >= m) w = 0.f;
            uint4 v = *(const uint4*)&H[(long)s * NCOL + c];
            fma8(acc, v, w);
        }
        if (nm <= 0) break;
        float wvn = 0.f;
        if (pe < nm) wvn = __expf(lrelu(as_[svn * HEADS + ph] + ad_p));
        dsum += wvn;
        sv = svn; wv = wvn; m = nm; base = nbase;
    }

    // denominator reduction (producer layout) and broadcast to consuming head
    if (HEADS == 1) {
#pragma unroll
        for (int msk = 1; msk < 64; msk <<= 1) dsum += __shfl_xor(dsum, msk);
    } else {
#pragma unroll
        for (int msk = 1; msk < 16; msk <<= 1) dsum += __shfl_xor(dsum, msk);
        dsum = __shfl(dsum, SB);
    }
    // fold accumulators across sub-wave groups
#pragma unroll
    for (int msk = LPE; msk < 64; msk <<= 1) {
#pragma unroll
        for (int i = 0; i < 8; i++) acc[i] += __shfl_xor(acc[i], msk);
    }
    // self loop (after fold: once per channel)
    {
        float wself = __expf(lrelu(as_[d * HEADS + hc] + ad_[d * HEADS + hc]));
        dsum += wself;
        uint4 vs = *(const uint4*)&H[(long)d * NCOL + c];
        fma8(acc, vs, wself);
    }
    float inv = 1.f / (dsum + 1e-16f);
    if (lane < LPE) {
        float4 r0, r1;
        r0.x = acc[0] * inv + bias[c + 0]; r0.y = acc[1] * inv + bias[c + 1];
        r0.z = acc[2] * inv + bias[c + 2]; r0.w = acc[3] * inv + bias[c + 3];
        r1.x = acc[4] * inv + bias[c + 4]; r1.y = acc[5] * inv + bias[c + 5];
        r1.z = acc[6] * inv + bias[c + 6]; r1.w = acc[7] * inv + bias[c + 7];
        if (LRELU) {
            r0.x = lrelu(r0.x); r0.y = lrelu(r0.y); r0.z = lrelu(r0.z); r0.w = lrelu(r0.w);
            r1.x = lrelu(r1.x); r1.y = lrelu(r1.y); r1.z = lrelu(r1.z); r1.w = lrelu(r1.w);
        }
        *(float4*)&out[(long)d * NCOL + c] = r0;
        *(float4*)&out[(long)d * NCOL + c + 4] = r1;
    }
}

static inline int nblk(long total) { return (int)((total + 255) / 256); }

extern "C" void kernel_launch(void* const* d_in, const int* in_sizes, int n_in,
                              void* d_out, int out_size, void* d_ws, size_t ws_size,
                              hipStream_t stream) {
    const float* x    = (const float*)d_in[0];
    const int*   ei   = (const int*)d_in[1];   // [2, NEDGES]
    const float* W1   = (const float*)d_in[2];
    const float* as1w = (const float*)d_in[3];
    const float* ad1w = (const float*)d_in[4];
    const float* b1   = (const float*)d_in[5];
    const float* W2   = (const float*)d_in[6];
    const float* as2w = (const float*)d_in[7];
    const float* ad2w = (const float*)d_in[8];
    const float* b2   = (const float*)d_in[9];
    float* out = (float*)d_out;

    char* wsb = (char*)d_ws;
    size_t o = 0;
    __half* h1   = (__half*)(wsb + o); o += (size_t)NNODES * 128 * 2;  // 12.8 MB; h2 aliases
    float* x2    = (float*)(wsb + o);  o += (size_t)NNODES * 128 * 4;  // 25.6 MB
    float* a_src1 = (float*)(wsb + o); o += (size_t)NNODES * 4 * 4;
    float* a_dst1 = (float*)(wsb + o); o += (size_t)NNODES * 4 * 4;
    float* a_src2 = (float*)(wsb + o); o += (size_t)NNODES * 4;
    float* a_dst2 = (float*)(wsb + o); o += (size_t)NNODES * 4;
    int* counts = (int*)(wsb + o); o += (size_t)NNODES * 4;
    int* offs   = (int*)(wsb + o); o += (size_t)NNODES * 4;
    int* cursor = (int*)(wsb + o); o += (size_t)NNODES * 4;
    int* bsums  = (int*)(wsb + o); o += 1024;
    int* ssrc   = (int*)(wsb + o); o += (size_t)NEDGES * 4;
    __half* h2 = h1;   // reuse: h1 dead after layer-1 gather

    const int NB = (NNODES + 255) / 256;   // scan blocks (196)
    const int GB = (NNODES + 63) / 64;     // gemm blocks (782)

    // ---- CSR build (dst-sorted src list) ----
    hipMemsetAsync(counts, 0, sizeof(int) * NNODES, stream);
    hist_kernel<<<nblk(NEDGES), 256, 0, stream>>>(ei, counts);
    scan1_kernel<<<NB, 256, 0, stream>>>(counts, offs, bsums, NNODES);
    scan2_kernel<<<1, 256, 0, stream>>>(bsums, NB);
    scan3_kernel<<<NB, 256, 0, stream>>>(offs, bsums, cursor, NNODES);
    scatter_kernel<<<nblk(NEDGES), 256, 0, stream>>>(ei, cursor, ssrc);

    // ---- layer 1 ----
    gemm_att_kernel<128, 4><<<GB, 256, 0, stream>>>(x, W1, as1w, ad1w, h1, a_src1, a_dst1, NNODES);
    gather_kernel<4, 128, 1><<<nblk((long)NNODES * 64), 256, 0, stream>>>(
        ssrc, offs, cursor, a_src1, a_dst1, h1, b1, x2, NNODES);

    // ---- layer 2 ----
    gemm_att_kernel<64, 1><<<GB, 256, 0, stream>>>(x2, W2, as2w, ad2w, h2, a_src2, a_dst2, NNODES);
    gather_kernel<1, 64, 0><<<nblk((long)NNODES * 64), 256, 0, stream>>>(
        ssrc, offs, cursor, a_src2, a_dst2, h2, b2, out, NNODES);
}

// Round 8
// 208.613 us; speedup vs baseline: 12.0071x; 1.1458x over previous
//
#include <hip/hip_runtime.h>
#include <hip/hip_fp16.h>

#define NNODES 50000
#define NEDGES 800000
#define NSLOPE 0.2f
#define NBUCK 12500     // NNODES/4 buckets, 4 dsts each
#define BCAP 192        // slots per bucket (mean fill 64)

__device__ __forceinline__ float lrelu(float x) { return x > 0.f ? x : NSLOPE * x; }

// unpack 8 halves (uint4) and accumulate w * v into acc[0..7]
__device__ __forceinline__ void fma8(float* acc, uint4 v, float w) {
    __half2 p0 = *(__half2*)&v.x, p1 = *(__half2*)&v.y;
    __half2 p2 = *(__half2*)&v.z, p3 = *(__half2*)&v.w;
    float2 f;
    f = __half22float2(p0); acc[0] += w * f.x; acc[1] += w * f.y;
    f = __half22float2(p1); acc[2] += w * f.x; acc[3] += w * f.y;
    f = __half22float2(p2); acc[4] += w * f.x; acc[5] += w * f.y;
    f = __half22float2(p3); acc[6] += w * f.x; acc[7] += w * f.y;
}

// ---------------- fused GEMM + attention-dot ----------------
template<int NCOL, int HEADS>
__global__ __launch_bounds__(256) void gemm_att_kernel(
    const float* __restrict__ A, const float* __restrict__ W,
    const float* __restrict__ atts, const float* __restrict__ attd,
    __half* __restrict__ H, float* __restrict__ as_, float* __restrict__ ad_,
    int nrows) {
    constexpr int LG = NCOL / 4;
    constexpr int GROUPS = 256 / LG;
    constexpr int RPT = 64 / GROUPS;
    constexpr int CH = NCOL / HEADS;
    constexpr int HL = CH / 4;
    constexpr int LDAP = 132;
    __shared__ float Alds[64 * LDAP];
    int t = threadIdx.x;
    long r0 = (long)blockIdx.x * 64;
    long abase = r0 * 128;
    long alimit = (long)nrows * 128;
#pragma unroll
    for (int i = 0; i < 8; i++) {
        int off = i * 1024 + t * 4;
        float4 v = make_float4(0.f, 0.f, 0.f, 0.f);
        if (abase + off < alimit) v = *(const float4*)&A[abase + off];
        int row = off >> 7, col = off & 127;
        *(float4*)&Alds[row * LDAP + col] = v;
    }
    __syncthreads();

    int l = t % LG, g = t / LG;
    int c = l * 4;
    int rb = g * RPT;
    float4 acc[RPT];
#pragma unroll
    for (int i = 0; i < RPT; i++) acc[i] = make_float4(0.f, 0.f, 0.f, 0.f);

    for (int k0 = 0; k0 < 128; k0 += 4) {
        float4 w0 = *(const float4*)&W[(k0 + 0) * NCOL + c];
        float4 w1 = *(const float4*)&W[(k0 + 1) * NCOL + c];
        float4 w2 = *(const float4*)&W[(k0 + 2) * NCOL + c];
        float4 w3 = *(const float4*)&W[(k0 + 3) * NCOL + c];
#pragma unroll
        for (int i = 0; i < RPT; i++) {
            float4 a = *(const float4*)&Alds[(rb + i) * LDAP + k0];
            acc[i].x += a.x * w0.x + a.y * w1.x + a.z * w2.x + a.w * w3.x;
            acc[i].y += a.x * w0.y + a.y * w1.y + a.z * w2.y + a.w * w3.y;
            acc[i].z += a.x * w0.z + a.y * w1.z + a.z * w2.z + a.w * w3.z;
            acc[i].w += a.x * w0.w + a.y * w1.w + a.z * w2.w + a.w * w3.w;
        }
    }

    float4 asw = *(const float4*)&atts[c];
    float4 adw = *(const float4*)&attd[c];
#pragma unroll
    for (int i = 0; i < RPT; i++) {
        long row = r0 + rb + i;
        float ps = acc[i].x * asw.x + acc[i].y * asw.y + acc[i].z * asw.z + acc[i].w * asw.w;
        float pd = acc[i].x * adw.x + acc[i].y * adw.y + acc[i].z * adw.z + acc[i].w * adw.w;
#pragma unroll
        for (int m = 1; m < HL; m <<= 1) {
            ps += __shfl_xor(ps, m);
            pd += __shfl_xor(pd, m);
        }
        if (row < nrows) {
            __half2 p0 = __floats2half2_rn(acc[i].x, acc[i].y);
            __half2 p1 = __floats2half2_rn(acc[i].z, acc[i].w);
            uint2 pk = make_uint2(*(unsigned*)&p0, *(unsigned*)&p1);
            *(uint2*)&H[row * NCOL + c] = pk;
            if ((l & (HL - 1)) == 0) {
                int h = c / CH;
                as_[row * HEADS + h] = ps;
                ad_[row * HEADS + h] = pd;
            }
        }
    }
}

// ---------------- bucketed CSR build ----------------
// pass 1: append packed (s | dlocal<<16) to bucket dst>>2
__global__ __launch_bounds__(256) void bucket_append_kernel(
    const int* __restrict__ ei, int* __restrict__ bcursor, unsigned* __restrict__ staging) {
    int e = blockIdx.x * 256 + threadIdx.x;
    if (e >= NEDGES) return;
    int s = ei[e], d = ei[NEDGES + e];
    int b = d >> 2;
    int pos = atomicAdd(&bcursor[b], 1);
    if (pos < BCAP) staging[b * BCAP + pos] = (unsigned)s | ((unsigned)(d & 3) << 16);
}

// pass 2: one wave per bucket: per-dst counts (register + shfl reduce)
__global__ __launch_bounds__(256) void bucket_count_kernel(
    const unsigned* __restrict__ staging, const int* __restrict__ bcursor,
    int* __restrict__ counts) {
    int w = threadIdx.x >> 6, lane = threadIdx.x & 63;
    int b = blockIdx.x * 4 + w;
    int n = bcursor[b]; if (n > BCAP) n = BCAP;
    int c0 = 0, c1 = 0, c2 = 0, c3 = 0;
    for (int i = lane; i < n; i += 64) {
        unsigned v = staging[b * BCAP + i];
        int dl = (v >> 16) & 3;
        c0 += (dl == 0); c1 += (dl == 1); c2 += (dl == 2); c3 += (dl == 3);
    }
#pragma unroll
    for (int m = 1; m < 64; m <<= 1) {
        c0 += __shfl_xor(c0, m); c1 += __shfl_xor(c1, m);
        c2 += __shfl_xor(c2, m); c3 += __shfl_xor(c3, m);
    }
    if (lane < 4) {
        int cc = (lane == 0) ? c0 : (lane == 1) ? c1 : (lane == 2) ? c2 : c3;
        counts[b * 4 + lane] = cc;
    }
}

// ---------------- scans (offs, ends) ----------------
__global__ void scan1_kernel(const int* __restrict__ counts, int* __restrict__ offs,
                             int* __restrict__ bsums, int n) {
    __shared__ int tmp[256];
    int i = blockIdx.x * 256 + threadIdx.x;
    int v = (i < n) ? counts[i] : 0;
    tmp[threadIdx.x] = v;
    __syncthreads();
    for (int off = 1; off < 256; off <<= 1) {
        int t = (threadIdx.x >= off) ? tmp[threadIdx.x - off] : 0;
        __syncthreads();
        tmp[threadIdx.x] += t;
        __syncthreads();
    }
    if (i < n) offs[i] = tmp[threadIdx.x] - v;
    if (threadIdx.x == 255) bsums[blockIdx.x] = tmp[255];
}

__global__ void scan2_kernel(int* __restrict__ bsums, int nb) {
    __shared__ int tmp[256];
    int v = (threadIdx.x < nb) ? bsums[threadIdx.x] : 0;
    tmp[threadIdx.x] = v;
    __syncthreads();
    for (int off = 1; off < 256; off <<= 1) {
        int t = (threadIdx.x >= off) ? tmp[threadIdx.x - off] : 0;
        __syncthreads();
        tmp[threadIdx.x] += t;
        __syncthreads();
    }
    if (threadIdx.x < nb) bsums[threadIdx.x] = tmp[threadIdx.x] - v;
}

__global__ void scan3_kernel(int* __restrict__ offs, const int* __restrict__ bsums,
                             const int* __restrict__ counts, int* __restrict__ ends, int n) {
    int i = blockIdx.x * 256 + threadIdx.x;
    if (i >= n) return;
    int o = offs[i] + bsums[blockIdx.x];
    offs[i] = o;
    ends[i] = o + counts[i];
}

// pass 3: one wave per bucket: place entries via 4 LDS cursors; dense writes
__global__ __launch_bounds__(256) void bucket_scatter_kernel(
    const unsigned* __restrict__ staging, const int* __restrict__ bcursor,
    const int* __restrict__ offs, int* __restrict__ ssrc) {
    __shared__ int lcur[16];
    int w = threadIdx.x >> 6, lane = threadIdx.x & 63;
    int b = blockIdx.x * 4 + w;
    if (lane < 4) lcur[w * 4 + lane] = offs[b * 4 + lane];
    __syncthreads();
    int n = bcursor[b]; if (n > BCAP) n = BCAP;
    for (int i = lane; i < n; i += 64) {
        unsigned v = staging[b * BCAP + i];
        int dl = (v >> 16) & 3;
        int pos = atomicAdd(&lcur[w * 4 + dl], 1);
        ssrc[pos] = (int)(v & 0xFFFFu);
    }
}

// ---------------- gather: one wave per dst node, fp16 rows ----------------
template<int HEADS, int NCOL, int LRELU>
__global__ __launch_bounds__(256) void gather_kernel(
    const int* __restrict__ ssrc, const int* __restrict__ offs,
    const int* __restrict__ ends, const float* __restrict__ as_,
    const float* __restrict__ ad_, const __half* __restrict__ H,
    const float* __restrict__ bias, float* __restrict__ out, int n) {
    constexpr int CHUNK = 64 / HEADS;
    constexpr int LPE = NCOL / 8;
    constexpr int EPI = 64 / LPE;
    int wave = (blockIdx.x * blockDim.x + threadIdx.x) >> 6;
    if (wave >= n) return;
    int lane = threadIdx.x & 63;
    int d = wave;
    int sub = lane / LPE;
    int c = (lane % LPE) * 8;
    int hc = (HEADS == 1) ? 0 : (c >> 5);
    int SB = hc * CHUNK;
    int pe = (HEADS == 1) ? lane : (lane % CHUNK);
    int ph = (HEADS == 1) ? 0 : (lane / CHUNK);
    float ad_p = ad_[d * HEADS + ph];
    float acc[8];
#pragma unroll
    for (int i = 0; i < 8; i++) acc[i] = 0.f;
    float dsum = 0.f;
    int start = offs[d], end = ends[d];

    int base = start;
    int m = end - base; if (m > CHUNK) m = CHUNK;
    int sv = 0; float wv = 0.f;
    if (m > 0) {
        if (pe < m) {
            sv = ssrc[base + pe];
            wv = __expf(lrelu(as_[sv * HEADS + ph] + ad_p));
        }
        dsum += wv;
    }
    while (m > 0) {
        int nbase = base + CHUNK;
        int nm = end - nbase; if (nm > CHUNK) nm = CHUNK;
        int svn = 0;
        if (nm > 0 && pe < nm) svn = ssrc[nbase + pe];
        int i = 0;
        for (; i + 4 * EPI <= m; i += 4 * EPI) {
            int i0 = i + sub, i1 = i + EPI + sub, i2 = i + 2 * EPI + sub, i3 = i + 3 * EPI + sub;
            int s0 = __shfl(sv, SB + i0);
            int s1 = __shfl(sv, SB + i1);
            int s2 = __shfl(sv, SB + i2);
            int s3 = __shfl(sv, SB + i3);
            uint4 v0 = *(const uint4*)&H[(long)s0 * NCOL + c];
            uint4 v1 = *(const uint4*)&H[(long)s1 * NCOL + c];
            uint4 v2 = *(const uint4*)&H[(long)s2 * NCOL + c];
            uint4 v3 = *(const uint4*)&H[(long)s3 * NCOL + c];
            float w0 = __shfl(wv, SB + i0);
            float w1 = __shfl(wv, SB + i1);
            float w2 = __shfl(wv, SB + i2);
            float w3 = __shfl(wv, SB + i3);
            fma8(acc, v0, w0); fma8(acc, v1, w1);
            fma8(acc, v2, w2); fma8(acc, v3, w3);
        }
        for (; i < m; i += EPI) {
            int idx = i + sub;
            int cl = (idx < m) ? idx : (m - 1);
            int s = __shfl(sv, SB + cl);
            float w = __shfl(wv, SB + cl);
            if (idx >= m) w = 0.f;
            uint4 v = *(const uint4*)&H[(long)s * NCOL + c];
            fma8(acc, v, w);
        }
        if (nm <= 0) break;
        float wvn = 0.f;
        if (pe < nm) wvn = __expf(lrelu(as_[svn * HEADS + ph] + ad_p));
        dsum += wvn;
        sv = svn; wv = wvn; m = nm; base = nbase;
    }

    if (HEADS == 1) {
#pragma unroll
        for (int msk = 1; msk < 64; msk <<= 1) dsum += __shfl_xor(dsum, msk);
    } else {
#pragma unroll
        for (int msk = 1; msk < 16; msk <<= 1) dsum += __shfl_xor(dsum, msk);
        dsum = __shfl(dsum, SB);
    }
#pragma unroll
    for (int msk = LPE; msk < 64; msk <<= 1) {
#pragma unroll
        for (int i = 0; i < 8; i++) acc[i] += __shfl_xor(acc[i], msk);
    }
    {
        float wself = __expf(lrelu(as_[d * HEADS + hc] + ad_[d * HEADS + hc]));
        dsum += wself;
        uint4 vs = *(const uint4*)&H[(long)d * NCOL + c];
        fma8(acc, vs, wself);
    }
    float inv = 1.f / (dsum + 1e-16f);
    if (lane < LPE) {
        float4 r0, r1;
        r0.x = acc[0] * inv + bias[c + 0]; r0.y = acc[1] * inv + bias[c + 1];
        r0.z = acc[2] * inv + bias[c + 2]; r0.w = acc[3] * inv + bias[c + 3];
        r1.x = acc[4] * inv + bias[c + 4]; r1.y = acc[5] * inv + bias[c + 5];
        r1.z = acc[6] * inv + bias[c + 6]; r1.w = acc[7] * inv + bias[c + 7];
        if (LRELU) {
            r0.x = lrelu(r0.x); r0.y = lrelu(r0.y); r0.z = lrelu(r0.z); r0.w = lrelu(r0.w);
            r1.x = lrelu(r1.x); r1.y = lrelu(r1.y); r1.z = lrelu(r1.z); r1.w = lrelu(r1.w);
        }
        *(float4*)&out[(long)d * NCOL + c] = r0;
        *(float4*)&out[(long)d * NCOL + c + 4] = r1;
    }
}

static inline int nblk(long total) { return (int)((total + 255) / 256); }

extern "C" void kernel_launch(void* const* d_in, const int* in_sizes, int n_in,
                              void* d_out, int out_size, void* d_ws, size_t ws_size,
                              hipStream_t stream) {
    const float* x    = (const float*)d_in[0];
    const int*   ei   = (const int*)d_in[1];   // [2, NEDGES]
    const float* W1   = (const float*)d_in[2];
    const float* as1w = (const float*)d_in[3];
    const float* ad1w = (const float*)d_in[4];
    const float* b1   = (const float*)d_in[5];
    const float* W2   = (const float*)d_in[6];
    const float* as2w = (const float*)d_in[7];
    const float* ad2w = (const float*)d_in[8];
    const float* b2   = (const float*)d_in[9];
    float* out = (float*)d_out;

    char* wsb = (char*)d_ws;
    size_t o = 0;
    __half* h1    = (__half*)(wsb + o); o += (size_t)NNODES * 128 * 2;   // 12.8 MB; h2 aliases
    float* x2     = (float*)(wsb + o);  o += (size_t)NNODES * 128 * 4;   // 25.6 MB
    float* a_src1 = (float*)(wsb + o);  o += (size_t)NNODES * 4 * 4;
    float* a_dst1 = (float*)(wsb + o);  o += (size_t)NNODES * 4 * 4;
    float* a_src2 = (float*)(wsb + o);  o += (size_t)NNODES * 4;
    float* a_dst2 = (float*)(wsb + o);  o += (size_t)NNODES * 4;
    int* counts  = (int*)(wsb + o); o += (size_t)NNODES * 4;
    int* offs    = (int*)(wsb + o); o += (size_t)NNODES * 4;
    int* ends    = (int*)(wsb + o); o += (size_t)NNODES * 4;
    int* bsums   = (int*)(wsb + o); o += 1024;
    int* ssrc    = (int*)(wsb + o); o += (size_t)NEDGES * 4;
    int* bcursor = (int*)(wsb + o); o += (size_t)NBUCK * 4;
    unsigned* staging = (unsigned*)(wsb + o); o += (size_t)NBUCK * BCAP * 4;  // 9.6 MB
    __half* h2 = h1;

    const int NB = (NNODES + 255) / 256;   // 196
    const int GB = (NNODES + 63) / 64;     // 782
    const int BB = NBUCK / 4;              // 3125 (wave per bucket)

    // ---- bucketed CSR build ----
    hipMemsetAsync(bcursor, 0, sizeof(int) * NBUCK, stream);
    bucket_append_kernel<<<nblk(NEDGES), 256, 0, stream>>>(ei, bcursor, staging);
    bucket_count_kernel<<<BB, 256, 0, stream>>>(staging, bcursor, counts);
    scan1_kernel<<<NB, 256, 0, stream>>>(counts, offs, bsums, NNODES);
    scan2_kernel<<<1, 256, 0, stream>>>(bsums, NB);
    scan3_kernel<<<NB, 256, 0, stream>>>(offs, bsums, counts, ends, NNODES);
    bucket_scatter_kernel<<<BB, 256, 0, stream>>>(staging, bcursor, offs, ssrc);

    // ---- layer 1 ----
    gemm_att_kernel<128, 4><<<GB, 256, 0, stream>>>(x, W1, as1w, ad1w, h1, a_src1, a_dst1, NNODES);
    gather_kernel<4, 128, 1><<<nblk((long)NNODES * 64), 256, 0, stream>>>(
        ssrc, offs, ends, a_src1, a_dst1, h1, b1, x2, NNODES);

    // ---- layer 2 ----
    gemm_att_kernel<64, 1><<<GB, 256, 0, stream>>>(x2, W2, as2w, ad2w, h2, a_src2, a_dst2, NNODES);
    gather_kernel<1, 64, 0><<<nblk((long)NNODES * 64), 256, 0, stream>>>(
        ssrc, offs, ends, a_src2, a_dst2, h2, b2, out, NNODES);
}